// Round 20
// baseline (673.747 us; speedup 1.0000x reference)
//
#include <hip/hip_runtime.h>
#include <math.h>
#include <stdint.h>

#define N_CTX 4096
#define DIM 512
#define NPERS 16
#define KTOT (NPERS * DIM)   // 8192
#define EPS_NN 0.1f
#define TOPK_K 30

#define DELTA 4e-4f          // ambiguity margin. GEMM-vs-chain error max ~3e-5
                             // over 16.7M elems -> >=6x margin at 4e-4.
#define CAP 64               // max candidates per row

#define BM 128               // MFMA output tile
#define BK 64                // K-step (bf16 elems)
#define NKSTEP (KTOT / BK)   // 128
#define CHUNK 16384          // bytes per (panel, k-step) LDS image

typedef __attribute__((ext_vector_type(8))) short bfrag;   // 8 bf16 = 4 VGPR
typedef __attribute__((ext_vector_type(4))) float f32x4;

// round-to-nearest-even float -> bf16 bits
__device__ __forceinline__ unsigned short f2bf(float f) {
  unsigned u = __float_as_uint(f);
  unsigned r = u + 0x7FFFu + ((u >> 16) & 1u);
  return (unsigned short)(r >> 16);
}

#define SWZ(r, b) ((b) ^ (((r) & 7) << 4))

// stage 1 KB: 64 lanes x 16 B. ldst = wave-uniform LDS base; HW adds lane*16.
__device__ __forceinline__ void stage1k(const char* gsrc, char* ldst, int lane) {
#if __has_builtin(__builtin_amdgcn_global_load_lds)
  __builtin_amdgcn_global_load_lds(
      (const __attribute__((address_space(1))) unsigned int*)(uintptr_t)(gsrc + lane * 16),
      (__attribute__((address_space(3))) unsigned int*)(uintptr_t)ldst, 16, 0, 0);
#else
  *reinterpret_cast<uint4*>(ldst + lane * 16) =
      *reinterpret_cast<const uint4*>(gsrc + lane * 16);
#endif
}

// ---------------------------------------------------------------------------
// Kernel 1 (fallback only): invr[p][n] = 0.25 / max(||c_n * w_p||, 1e-12)
// ---------------------------------------------------------------------------
__global__ __launch_bounds__(256) void norms_kernel(
    const float* __restrict__ ctx, const float* __restrict__ w,
    float* __restrict__ invr) {
  int wid = threadIdx.x >> 6;
  int lane = threadIdx.x & 63;
  int gid = blockIdx.x * 4 + wid;          // 0 .. 65535
  int p = gid >> 12;
  int n = gid & (N_CTX - 1);
  const float4* c4 = reinterpret_cast<const float4*>(ctx + (size_t)n * DIM + lane * 8);
  const float4* w4 = reinterpret_cast<const float4*>(w + (size_t)p * DIM + lane * 8);
  float4 c0 = c4[0], c1 = c4[1];
  float4 w0 = w4[0], w1 = w4[1];
  float s = 0.f, v;
  v = c0.x * w0.x; s = fmaf(v, v, s);
  v = c0.y * w0.y; s = fmaf(v, v, s);
  v = c0.z * w0.z; s = fmaf(v, v, s);
  v = c0.w * w0.w; s = fmaf(v, v, s);
  v = c1.x * w1.x; s = fmaf(v, v, s);
  v = c1.y * w1.y; s = fmaf(v, v, s);
  v = c1.z * w1.z; s = fmaf(v, v, s);
  v = c1.w * w1.w; s = fmaf(v, v, s);
#pragma unroll
  for (int off = 32; off; off >>= 1) s += __shfl_down(s, off, 64);
  if (lane == 0) invr[(size_t)p * N_CTX + n] = 0.25f / fmaxf(sqrtf(s), 1e-12f);
}

// ---------------------------------------------------------------------------
// Kernel 1+1b FUSED: norms (bit-identical chain) + bf16-hi split into the
// panel-swizzled LDS-image layout. UNCHANGED from R16-R19.
// ---------------------------------------------------------------------------
__global__ __launch_bounds__(256) void split_norms_kernel(
    const float* __restrict__ ctx, const float* __restrict__ w,
    float* __restrict__ invr, unsigned short* __restrict__ Fhi) {
  const int tid = blockIdx.x * 256 + threadIdx.x;   // 0 .. 4096*64-1
  const int n = tid >> 6;                 // wave-uniform (wave = 64 aligned)
  const int db = tid & 63;                // lane = 8-col block within 512-dim
  const int d0 = db * 8;
  const int P = n >> 7;                   // panel
  const int r = n & 127;                  // row within panel
  const int sl = db & 7;                  // 16B slot within k-step chunk
  const int swzoff = r * 128 + ((sl * 16) ^ ((r & 7) << 4));

  const float4 c0 = *reinterpret_cast<const float4*>(ctx + (size_t)n * DIM + d0);
  const float4 c1 = *reinterpret_cast<const float4*>(ctx + (size_t)n * DIM + d0 + 4);

#pragma unroll
  for (int p = 0; p < NPERS; ++p) {
    const float4 w0 = *reinterpret_cast<const float4*>(w + (size_t)p * DIM + d0);
    const float4 w1 = *reinterpret_cast<const float4*>(w + (size_t)p * DIM + d0 + 4);

    float pr[8] = {c0.x * w0.x, c0.y * w0.y, c0.z * w0.z, c0.w * w0.w,
                   c1.x * w1.x, c1.y * w1.y, c1.z * w1.z, c1.w * w1.w};

    float s = 0.f;
#pragma unroll
    for (int j = 0; j < 8; ++j) s = fmaf(pr[j], pr[j], s);
#pragma unroll
    for (int off = 32; off; off >>= 1) s += __shfl_down(s, off, 64);
    const float stot = __shfl(s, 0, 64);
    const float sc = 0.25f / fmaxf(sqrtf(stot), 1e-12f);
    if (db == 0) invr[(size_t)p * N_CTX + n] = sc;

    unsigned hb[8];
#pragma unroll
    for (int j = 0; j < 8; ++j) hb[j] = f2bf(pr[j] * sc);   // == (c*w)*sc
    uint4 hv = make_uint4(hb[0] | (hb[1] << 16), hb[2] | (hb[3] << 16),
                          hb[4] | (hb[5] << 16), hb[6] | (hb[7] << 16));
    const int kstep = p * 8 + (db >> 3);           // k-step index
    const size_t base = (size_t)(P * 128 + kstep) * CHUNK + swzoff;
    *reinterpret_cast<uint4*>((char*)Fhi + base) = hv;
  }
}

// ---------------------------------------------------------------------------
// Kernel 2 (fast): att ~= Fhi Fhi^T via bf16 MFMA, SINGLE product.
// UNCHANGED from R16 (validated).
// ---------------------------------------------------------------------------
__global__ __launch_bounds__(256, 3) void att_gemm_fast(
    const unsigned short* __restrict__ Fhi, float* __restrict__ out) {
  const int bid0 = blockIdx.x;
  int bid = (bid0 & 7) * 66 + (bid0 >> 3);   // XCD-contiguous tile runs
  int by = 0;
  while (bid >= (by + 1) * 32 - ((by + 1) * by) / 2) ++by;
  const int bx = by + (bid - (by * 32 - (by * (by - 1)) / 2));

  __shared__ __align__(16) char Ahi[CHUNK];
  __shared__ __align__(16) char Bhi[CHUNK];

  const int t = threadIdx.x;
  const int lane = t & 63, wid = t >> 6;
  const int wr = wid >> 1, wc = wid & 1;
  const int woff = __builtin_amdgcn_readfirstlane(wid * 4096);

  const char* gAh = (const char*)Fhi + (size_t)by * NKSTEP * CHUNK + woff;
  const char* gBh = (const char*)Fhi + (size_t)bx * NKSTEP * CHUNK + woff;

  f32x4 acc[4][4] = {};

  for (int s = 0; s < NKSTEP; ++s) {
    const size_t so = (size_t)s * CHUNK;
#pragma unroll
    for (int i = 0; i < 4; ++i) {
      stage1k(gAh + so + i * 1024, Ahi + woff + i * 1024, lane);
      stage1k(gBh + so + i * 1024, Bhi + woff + i * 1024, lane);
    }
    __syncthreads();

#pragma unroll
    for (int ks = 0; ks < 2; ++ks) {
      const int kb = ks * 64 + (lane >> 4) * 16;
      bfrag ah[4], bh[4];
#pragma unroll
      for (int m = 0; m < 4; ++m) {
        const int r = wr * 64 + m * 16 + (lane & 15);
        ah[m] = *reinterpret_cast<const bfrag*>(Ahi + r * 128 + SWZ(r, kb));
      }
#pragma unroll
      for (int n2 = 0; n2 < 4; ++n2) {
        const int r = wc * 64 + n2 * 16 + (lane & 15);
        bh[n2] = *reinterpret_cast<const bfrag*>(Bhi + r * 128 + SWZ(r, kb));
      }
#pragma unroll
      for (int m = 0; m < 4; ++m)
#pragma unroll
        for (int n2 = 0; n2 < 4; ++n2)
          acc[m][n2] = __builtin_amdgcn_mfma_f32_16x16x32_bf16(ah[m], bh[n2], acc[m][n2], 0, 0, 0);
    }
    __syncthreads();
  }

  const int Ro = by * BM, Co = bx * BM;
  const int col = lane & 15, rq = (lane >> 4) * 4;
#pragma unroll
  for (int m = 0; m < 4; ++m)
#pragma unroll
    for (int n2 = 0; n2 < 4; ++n2) {
      const int gr = Ro + wr * 64 + m * 16 + rq;
      const int gc = Co + wc * 64 + n2 * 16 + col;
#pragma unroll
      for (int j = 0; j < 4; ++j)
        out[(size_t)(gr + j) * N_CTX + gc] = acc[m][n2][j];
      if (bx != by) {
        *reinterpret_cast<float4*>(out + (size_t)gc * N_CTX + gr) =
            make_float4(acc[m][n2][0], acc[m][n2][1], acc[m][n2][2], acc[m][n2][3]);
      }
    }
}

// ---------------------------------------------------------------------------
// Kernel 2 (fallback): on-the-fly split + 3-product MFMA (ws too small path).
// ---------------------------------------------------------------------------
__device__ __forceinline__ void stage_half(char* __restrict__ hi_base,
                                           char* __restrict__ lo_base,
                                           const float4* cv, const float4* wv,
                                           float s, int r, int h) {
  unsigned hu[16], lu[16];
#pragma unroll
  for (int i = 0; i < 8; ++i) {
    float f[4] = {cv[i].x * wv[i].x * s, cv[i].y * wv[i].y * s,
                  cv[i].z * wv[i].z * s, cv[i].w * wv[i].w * s};
    unsigned hb[4], lb[4];
#pragma unroll
    for (int j = 0; j < 4; ++j) {
      hb[j] = f2bf(f[j]);
      float hf = __uint_as_float(hb[j] << 16);
      lb[j] = f2bf(f[j] - hf);
    }
    hu[2 * i] = hb[0] | (hb[1] << 16);
    hu[2 * i + 1] = hb[2] | (hb[3] << 16);
    lu[2 * i] = lb[0] | (lb[1] << 16);
    lu[2 * i + 1] = lb[2] | (lb[3] << 16);
  }
#pragma unroll
  for (int c = 0; c < 4; ++c) {
    int boff = r * 128 + SWZ(r, h * 64 + c * 16);
    *reinterpret_cast<uint4*>(hi_base + boff) =
        make_uint4(hu[4 * c], hu[4 * c + 1], hu[4 * c + 2], hu[4 * c + 3]);
    *reinterpret_cast<uint4*>(lo_base + boff) =
        make_uint4(lu[4 * c], lu[4 * c + 1], lu[4 * c + 2], lu[4 * c + 3]);
  }
}

__global__ __launch_bounds__(256, 2) void att_gemm(
    const float* __restrict__ ctx, const float* __restrict__ w,
    const float* __restrict__ invr, float* __restrict__ out) {
  const int bx = blockIdx.x, by = blockIdx.y;
  if (by > bx) return;

  __shared__ __align__(16) char Ahi[BM * 128];
  __shared__ __align__(16) char Alo[BM * 128];
  __shared__ __align__(16) char Bhi[BM * 128];
  __shared__ __align__(16) char Blo[BM * 128];

  const int t = threadIdx.x;
  const int lane = t & 63, wid = t >> 6;
  const int wr = wid >> 1, wc = wid & 1;
  const int Ro = by * BM, Co = bx * BM;
  const int srow = t >> 1;
  const int sh = t & 1;

  f32x4 acc[4][4] = {};

  for (int k0 = 0; k0 < KTOT; k0 += BK) {
    const int p = k0 >> 9;
    const int d0 = (k0 & (DIM - 1)) + sh * 32;

    float4 cva[8], cvb[8], wv[8];
    const float* wrow = w + (size_t)p * DIM + d0;
    const float* arow = ctx + (size_t)(Ro + srow) * DIM + d0;
    const float* brow = ctx + (size_t)(Co + srow) * DIM + d0;
#pragma unroll
    for (int i = 0; i < 8; ++i) {
      wv[i] = *reinterpret_cast<const float4*>(wrow + 4 * i);
      cva[i] = *reinterpret_cast<const float4*>(arow + 4 * i);
      cvb[i] = *reinterpret_cast<const float4*>(brow + 4 * i);
    }
    const float sA = invr[(size_t)p * N_CTX + Ro + srow];
    const float sB = invr[(size_t)p * N_CTX + Co + srow];

    __syncthreads();
    stage_half(Ahi, Alo, cva, wv, sA, srow, sh);
    stage_half(Bhi, Blo, cvb, wv, sB, srow, sh);
    __syncthreads();

#pragma unroll
    for (int ks = 0; ks < 2; ++ks) {
      const int kb = ks * 64 + (lane >> 4) * 16;
      bfrag ah[4], al[4], bh[4], bl[4];
#pragma unroll
      for (int m = 0; m < 4; ++m) {
        const int r = wr * 64 + m * 16 + (lane & 15);
        const int off = r * 128 + SWZ(r, kb);
        ah[m] = *reinterpret_cast<const bfrag*>(Ahi + off);
        al[m] = *reinterpret_cast<const bfrag*>(Alo + off);
      }
#pragma unroll
      for (int n = 0; n < 4; ++n) {
        const int r = wc * 64 + n * 16 + (lane & 15);
        const int off = r * 128 + SWZ(r, kb);
        bh[n] = *reinterpret_cast<const bfrag*>(Bhi + off);
        bl[n] = *reinterpret_cast<const bfrag*>(Blo + off);
      }
#pragma unroll
      for (int m = 0; m < 4; ++m)
#pragma unroll
        for (int n = 0; n < 4; ++n) {
          acc[m][n] = __builtin_amdgcn_mfma_f32_16x16x32_bf16(ah[m], bh[n], acc[m][n], 0, 0, 0);
          acc[m][n] = __builtin_amdgcn_mfma_f32_16x16x32_bf16(ah[m], bl[n], acc[m][n], 0, 0, 0);
          acc[m][n] = __builtin_amdgcn_mfma_f32_16x16x32_bf16(al[m], bh[n], acc[m][n], 0, 0, 0);
        }
    }
  }

  const int col = lane & 15, rq = (lane >> 4) * 4;
#pragma unroll
  for (int m = 0; m < 4; ++m)
#pragma unroll
    for (int n = 0; n < 4; ++n) {
      const int gr = Ro + wr * 64 + m * 16 + rq;
      const int gc = Co + wc * 64 + n * 16 + col;
#pragma unroll
      for (int j = 0; j < 4; ++j)
        out[(size_t)(gr + j) * N_CTX + gc] = acc[m][n][j];
      if (bx != by) {
        *reinterpret_cast<float4*>(out + (size_t)gc * N_CTX + gr) =
            make_float4(acc[m][n][0], acc[m][n][1], acc[m][n][2], acc[m][n][3]);
      }
    }
}

// ---------------------------------------------------------------------------
// Kernel 3: scan — UNCHANGED from R17-R19 (stores candV + nearEps flag).
// ---------------------------------------------------------------------------
__global__ __launch_bounds__(256) void topk_scan(
    float* __restrict__ att, int* __restrict__ candM,
    float* __restrict__ candV, int* __restrict__ cnt_g) {
  __shared__ unsigned red[2][4];
  __shared__ int lcnt, lg;

  const int n = blockIdx.x;
  const int t = threadIdx.x;
  const int wid = t >> 6, lane = t & 63;
  float* row = att + (size_t)n * N_CTX;

  float ar[16], tr[16];
  unsigned ur[16];
#pragma unroll
  for (int i = 0; i < 4; ++i) {
    float4 v4 = *reinterpret_cast<const float4*>(row + (size_t)(i * 256 + t) * 4);
    float tmp[4] = {v4.x, v4.y, v4.z, v4.w};
#pragma unroll
    for (int j = 0; j < 4; ++j) {
      float a = tmp[j];
      float tt = (a > EPS_NN) ? a : 0.0f;
      ar[i * 4 + j] = a;
      tr[i * 4 + j] = tt;
      ur[i * 4 + j] = __float_as_uint(tt);
    }
  }
  if (t == 0) { lcnt = 0; lg = 0; }

  unsigned lo = 0u, hi = 0x7F800000u;
  int buf = 0;
  while (lo < hi) {
    unsigned mid = lo + ((hi - lo) >> 1);
    unsigned c = 0;
#pragma unroll
    for (int i = 0; i < 16; ++i) c += (ur[i] > mid) ? 1u : 0u;
#pragma unroll
    for (int off = 32; off; off >>= 1) c += __shfl_down(c, off, 64);
    if (lane == 0) red[buf][wid] = c;
    __syncthreads();
    unsigned tot = red[buf][0] + red[buf][1] + red[buf][2] + red[buf][3];
    if (tot < TOPK_K) hi = mid; else lo = mid + 1;
    buf ^= 1;
  }
  const float vk = __uint_as_float(lo);
  const bool nearEps = (vk <= EPS_NN + 2.0f * DELTA);
  __syncthreads();   // lcnt/lg init visible

  unsigned myg = 0;
#pragma unroll
  for (int i = 0; i < 16; ++i) {
    const int blk = i >> 2, j = i & 3;
    const int m = (blk * 256 + t) * 4 + j;
    const float a = ar[i], tt = tr[i];
    const bool isEps = fabsf(a - EPS_NN) <= DELTA;
    const bool isOrd = (tt > 0.f) && (fabsf(tt - vk) <= DELTA);
    const bool cand = isOrd || (isEps && nearEps);
    const bool defIn = (tt > vk + DELTA) && !cand;
    tr[i] = defIn ? tt : 0.f;
    myg += defIn ? 1u : 0u;
    unsigned long long mask = __ballot(cand);
    if (mask) {
      int base = 0;
      if (lane == 0) base = atomicAdd(&lcnt, (int)__popcll(mask));
      base = __shfl(base, 0, 64);
      if (cand) {
        int pos = base + (int)__popcll(mask & ((1ull << lane) - 1ull));
        if (pos < CAP) {
          candM[n * CAP + pos] = m;
          candV[n * CAP + pos] = tt;
        }
      }
    }
  }
#pragma unroll
  for (int off = 32; off; off >>= 1) myg += __shfl_down(myg, off, 64);
  if (lane == 0) atomicAdd(&lg, (int)myg);

#pragma unroll
  for (int i = 0; i < 4; ++i) {
    *reinterpret_cast<float4*>(row + (size_t)(i * 256 + t) * 4) =
        make_float4(tr[i * 4], tr[i * 4 + 1], tr[i * 4 + 2], tr[i * 4 + 3]);
  }
  __syncthreads();
  if (t == 0) {
    cnt_g[4 * n] = (lcnt < CAP) ? lcnt : CAP;
    cnt_g[4 * n + 1] = lg;
    cnt_g[4 * n + 2] = nearEps ? 1 : 0;
  }
}

// ---------------------------------------------------------------------------
// Kernel 4: exact repair + select. R20: explicit 8x-float4 BATCHED loads —
// a fully-unrolled independent load block (24 loads pipeline in the memory
// system) followed by the fmafs in VERBATIM locked order (k ascending:
// batch b covers q=8b..8b+7, x->y->z->w) -> bit-identical values.
// Skip-path unchanged (R18 validated). Warm loop removed (R19 null).
// ---------------------------------------------------------------------------
__global__ __launch_bounds__(64) void repair_select(
    const float* __restrict__ ctx, const float* __restrict__ w,
    const float* __restrict__ invr, const int* __restrict__ candM,
    const float* __restrict__ candV, const int* __restrict__ cnt_g,
    float* __restrict__ att) {
  const int n = blockIdx.x;
  const int c = cnt_g[4 * n];
  if (c == 0) return;
  const int slots = TOPK_K - cnt_g[4 * n + 1];
  const int nearEps = cnt_g[4 * n + 2];
  const int j = threadIdx.x;

  if (c <= slots && !nearEps) {   // all candidates selected; approx values OK
    if (j < c) att[(size_t)n * N_CTX + candM[n * CAP + j]] = candV[n * CAP + j];
    return;
  }

  __shared__ float te_s[CAP];
  __shared__ int m_s[CAP];

  float te = -1.f;
  int m = -1;
  if (j < c) {
    m = candM[n * CAP + j];
    const float4* cn4 = reinterpret_cast<const float4*>(ctx + (size_t)n * DIM);
    const float4* cm4 = reinterpret_cast<const float4*>(ctx + (size_t)m * DIM);
    float e = 0.f;
    for (int p = 0; p < NPERS; ++p) {
      const float sA = invr[(size_t)p * N_CTX + n];
      const float sB = invr[(size_t)p * N_CTX + m];
      const float4* w4 = reinterpret_cast<const float4*>(w + (size_t)p * DIM);
      for (int b = 0; b < 16; ++b) {   // 16 batches of 8 float4 = 128 q's
        float4 A[8], B[8], G[8];
#pragma unroll
        for (int i = 0; i < 8; ++i) {
          A[i] = cn4[b * 8 + i];
          B[i] = cm4[b * 8 + i];
          G[i] = w4[b * 8 + i];
        }
#pragma unroll
        for (int i = 0; i < 8; ++i) {
          e = fmaf((A[i].x * G[i].x) * sA, (B[i].x * G[i].x) * sB, e);
          e = fmaf((A[i].y * G[i].y) * sA, (B[i].y * G[i].y) * sB, e);
          e = fmaf((A[i].z * G[i].z) * sA, (B[i].z * G[i].z) * sB, e);
          e = fmaf((A[i].w * G[i].w) * sA, (B[i].w * G[i].w) * sB, e);
        }
      }
    }
    te = (e > EPS_NN) ? e : 0.f;
  }
  m_s[j] = m;
  te_s[j] = te;
  __syncthreads();
  if (j < c) {
    int rank = 0;
    for (int i = 0; i < c; ++i) {
      if (i == j) continue;
      rank += ((te_s[i] > te) || (te_s[i] == te && m_s[i] < m)) ? 1 : 0;
    }
    if (rank < slots) att[(size_t)n * N_CTX + m] = te;
  }
}

// ---------------------------------------------------------------------------
extern "C" void kernel_launch(void* const* d_in, const int* in_sizes, int n_in,
                              void* d_out, int out_size, void* d_ws, size_t ws_size,
                              hipStream_t stream) {
  const float* ctx = (const float*)d_in[0];   // (4096, 512)
  const float* w   = (const float*)d_in[1];   // (16, 512)
  float* out = (float*)d_out;                 // (4096, 4096)

  // ws: invr 256KB | cnt_g 64KB | candM 1MB | candV 1MB | Fhi 64MB
  const size_t OFF_CNT = 262144;
  const size_t OFF_CAND = OFF_CNT + 65536;
  const size_t OFF_CV = OFF_CAND + 1048576;
  const size_t OFF_FHI = OFF_CV + 1048576;
  const size_t FSZ = (size_t)32 * NKSTEP * CHUNK;       // 67108864
  float* invr = (float*)d_ws;
  int* cnt_g = (int*)((char*)d_ws + OFF_CNT);
  int* candM = (int*)((char*)d_ws + OFF_CAND);
  float* candV = (float*)((char*)d_ws + OFF_CV);
  unsigned short* Fhi = (unsigned short*)((char*)d_ws + OFF_FHI);
  const bool haveF = ws_size >= OFF_FHI + FSZ;

  if (haveF) {
    split_norms_kernel<<<(N_CTX * 64) / 256, 256, 0, stream>>>(ctx, w, invr, Fhi);
    att_gemm_fast<<<528, 256, 0, stream>>>(Fhi, out);
  } else {
    norms_kernel<<<(NPERS * N_CTX) / 4, 256, 0, stream>>>(ctx, w, invr);
    dim3 grid(N_CTX / BM, N_CTX / BM);
    att_gemm<<<grid, 256, 0, stream>>>(ctx, w, invr, out);
  }

  topk_scan<<<N_CTX, 256, 0, stream>>>(out, candM, candV, cnt_g);
  repair_select<<<N_CTX, 64, 0, stream>>>(ctx, w, invr, candM, candV, cnt_g, out);
}

// Round 21
// 581.998 us; speedup vs baseline: 1.1576x; 1.1576x over previous
//
#include <hip/hip_runtime.h>
#include <math.h>
#include <stdint.h>

#define N_CTX 4096
#define DIM 512
#define NPERS 16
#define KTOT (NPERS * DIM)   // 8192
#define EPS_NN 0.1f
#define TOPK_K 30

#define DELTA 4e-4f          // scan ambiguity margin (GEMM-vs-chain, validated)
#define DELTA2 2e-5f         // refined-vs-chain margin (fp32 order noise ~3e-6)
#define CAP 64               // max candidates per row

#define BM 128               // MFMA output tile
#define BK 64                // K-step (bf16 elems)
#define NKSTEP (KTOT / BK)   // 128
#define CHUNK 16384          // bytes per (panel, k-step) LDS image

typedef __attribute__((ext_vector_type(8))) short bfrag;   // 8 bf16 = 4 VGPR
typedef __attribute__((ext_vector_type(4))) float f32x4;

// round-to-nearest-even float -> bf16 bits
__device__ __forceinline__ unsigned short f2bf(float f) {
  unsigned u = __float_as_uint(f);
  unsigned r = u + 0x7FFFu + ((u >> 16) & 1u);
  return (unsigned short)(r >> 16);
}

#define SWZ(r, b) ((b) ^ (((r) & 7) << 4))

// stage 1 KB: 64 lanes x 16 B. ldst = wave-uniform LDS base; HW adds lane*16.
__device__ __forceinline__ void stage1k(const char* gsrc, char* ldst, int lane) {
#if __has_builtin(__builtin_amdgcn_global_load_lds)
  __builtin_amdgcn_global_load_lds(
      (const __attribute__((address_space(1))) unsigned int*)(uintptr_t)(gsrc + lane * 16),
      (__attribute__((address_space(3))) unsigned int*)(uintptr_t)ldst, 16, 0, 0);
#else
  *reinterpret_cast<uint4*>(ldst + lane * 16) =
      *reinterpret_cast<const uint4*>(gsrc + lane * 16);
#endif
}

// ---------------------------------------------------------------------------
// Kernel 1 (fallback only): invr[p][n] = 0.25 / max(||c_n * w_p||, 1e-12)
// ---------------------------------------------------------------------------
__global__ __launch_bounds__(256) void norms_kernel(
    const float* __restrict__ ctx, const float* __restrict__ w,
    float* __restrict__ invr) {
  int wid = threadIdx.x >> 6;
  int lane = threadIdx.x & 63;
  int gid = blockIdx.x * 4 + wid;          // 0 .. 65535
  int p = gid >> 12;
  int n = gid & (N_CTX - 1);
  const float4* c4 = reinterpret_cast<const float4*>(ctx + (size_t)n * DIM + lane * 8);
  const float4* w4 = reinterpret_cast<const float4*>(w + (size_t)p * DIM + lane * 8);
  float4 c0 = c4[0], c1 = c4[1];
  float4 w0 = w4[0], w1 = w4[1];
  float s = 0.f, v;
  v = c0.x * w0.x; s = fmaf(v, v, s);
  v = c0.y * w0.y; s = fmaf(v, v, s);
  v = c0.z * w0.z; s = fmaf(v, v, s);
  v = c0.w * w0.w; s = fmaf(v, v, s);
  v = c1.x * w1.x; s = fmaf(v, v, s);
  v = c1.y * w1.y; s = fmaf(v, v, s);
  v = c1.z * w1.z; s = fmaf(v, v, s);
  v = c1.w * w1.w; s = fmaf(v, v, s);
#pragma unroll
  for (int off = 32; off; off >>= 1) s += __shfl_down(s, off, 64);
  if (lane == 0) invr[(size_t)p * N_CTX + n] = 0.25f / fmaxf(sqrtf(s), 1e-12f);
}

// ---------------------------------------------------------------------------
// Kernel 1+1b FUSED: norms (bit-identical chain) + bf16-hi split into the
// panel-swizzled LDS-image layout. UNCHANGED from R16-R20.
// ---------------------------------------------------------------------------
__global__ __launch_bounds__(256) void split_norms_kernel(
    const float* __restrict__ ctx, const float* __restrict__ w,
    float* __restrict__ invr, unsigned short* __restrict__ Fhi) {
  const int tid = blockIdx.x * 256 + threadIdx.x;   // 0 .. 4096*64-1
  const int n = tid >> 6;                 // wave-uniform (wave = 64 aligned)
  const int db = tid & 63;                // lane = 8-col block within 512-dim
  const int d0 = db * 8;
  const int P = n >> 7;                   // panel
  const int r = n & 127;                  // row within panel
  const int sl = db & 7;                  // 16B slot within k-step chunk
  const int swzoff = r * 128 + ((sl * 16) ^ ((r & 7) << 4));

  const float4 c0 = *reinterpret_cast<const float4*>(ctx + (size_t)n * DIM + d0);
  const float4 c1 = *reinterpret_cast<const float4*>(ctx + (size_t)n * DIM + d0 + 4);

#pragma unroll
  for (int p = 0; p < NPERS; ++p) {
    const float4 w0 = *reinterpret_cast<const float4*>(w + (size_t)p * DIM + d0);
    const float4 w1 = *reinterpret_cast<const float4*>(w + (size_t)p * DIM + d0 + 4);

    float pr[8] = {c0.x * w0.x, c0.y * w0.y, c0.z * w0.z, c0.w * w0.w,
                   c1.x * w1.x, c1.y * w1.y, c1.z * w1.z, c1.w * w1.w};

    float s = 0.f;
#pragma unroll
    for (int j = 0; j < 8; ++j) s = fmaf(pr[j], pr[j], s);
#pragma unroll
    for (int off = 32; off; off >>= 1) s += __shfl_down(s, off, 64);
    const float stot = __shfl(s, 0, 64);
    const float sc = 0.25f / fmaxf(sqrtf(stot), 1e-12f);
    if (db == 0) invr[(size_t)p * N_CTX + n] = sc;

    unsigned hb[8];
#pragma unroll
    for (int j = 0; j < 8; ++j) hb[j] = f2bf(pr[j] * sc);   // == (c*w)*sc
    uint4 hv = make_uint4(hb[0] | (hb[1] << 16), hb[2] | (hb[3] << 16),
                          hb[4] | (hb[5] << 16), hb[6] | (hb[7] << 16));
    const int kstep = p * 8 + (db >> 3);           // k-step index
    const size_t base = (size_t)(P * 128 + kstep) * CHUNK + swzoff;
    *reinterpret_cast<uint4*>((char*)Fhi + base) = hv;
  }
}

// ---------------------------------------------------------------------------
// Kernel 2 (fast): att ~= Fhi Fhi^T via bf16 MFMA, SINGLE product.
// UNCHANGED from R16 (validated).
// ---------------------------------------------------------------------------
__global__ __launch_bounds__(256, 3) void att_gemm_fast(
    const unsigned short* __restrict__ Fhi, float* __restrict__ out) {
  const int bid0 = blockIdx.x;
  int bid = (bid0 & 7) * 66 + (bid0 >> 3);   // XCD-contiguous tile runs
  int by = 0;
  while (bid >= (by + 1) * 32 - ((by + 1) * by) / 2) ++by;
  const int bx = by + (bid - (by * 32 - (by * (by - 1)) / 2));

  __shared__ __align__(16) char Ahi[CHUNK];
  __shared__ __align__(16) char Bhi[CHUNK];

  const int t = threadIdx.x;
  const int lane = t & 63, wid = t >> 6;
  const int wr = wid >> 1, wc = wid & 1;
  const int woff = __builtin_amdgcn_readfirstlane(wid * 4096);

  const char* gAh = (const char*)Fhi + (size_t)by * NKSTEP * CHUNK + woff;
  const char* gBh = (const char*)Fhi + (size_t)bx * NKSTEP * CHUNK + woff;

  f32x4 acc[4][4] = {};

  for (int s = 0; s < NKSTEP; ++s) {
    const size_t so = (size_t)s * CHUNK;
#pragma unroll
    for (int i = 0; i < 4; ++i) {
      stage1k(gAh + so + i * 1024, Ahi + woff + i * 1024, lane);
      stage1k(gBh + so + i * 1024, Bhi + woff + i * 1024, lane);
    }
    __syncthreads();

#pragma unroll
    for (int ks = 0; ks < 2; ++ks) {
      const int kb = ks * 64 + (lane >> 4) * 16;
      bfrag ah[4], bh[4];
#pragma unroll
      for (int m = 0; m < 4; ++m) {
        const int r = wr * 64 + m * 16 + (lane & 15);
        ah[m] = *reinterpret_cast<const bfrag*>(Ahi + r * 128 + SWZ(r, kb));
      }
#pragma unroll
      for (int n2 = 0; n2 < 4; ++n2) {
        const int r = wc * 64 + n2 * 16 + (lane & 15);
        bh[n2] = *reinterpret_cast<const bfrag*>(Bhi + r * 128 + SWZ(r, kb));
      }
#pragma unroll
      for (int m = 0; m < 4; ++m)
#pragma unroll
        for (int n2 = 0; n2 < 4; ++n2)
          acc[m][n2] = __builtin_amdgcn_mfma_f32_16x16x32_bf16(ah[m], bh[n2], acc[m][n2], 0, 0, 0);
    }
    __syncthreads();
  }

  const int Ro = by * BM, Co = bx * BM;
  const int col = lane & 15, rq = (lane >> 4) * 4;
#pragma unroll
  for (int m = 0; m < 4; ++m)
#pragma unroll
    for (int n2 = 0; n2 < 4; ++n2) {
      const int gr = Ro + wr * 64 + m * 16 + rq;
      const int gc = Co + wc * 64 + n2 * 16 + col;
#pragma unroll
      for (int j = 0; j < 4; ++j)
        out[(size_t)(gr + j) * N_CTX + gc] = acc[m][n2][j];
      if (bx != by) {
        *reinterpret_cast<float4*>(out + (size_t)gc * N_CTX + gr) =
            make_float4(acc[m][n2][0], acc[m][n2][1], acc[m][n2][2], acc[m][n2][3]);
      }
    }
}

// ---------------------------------------------------------------------------
// Kernel 2 (fallback): on-the-fly split + 3-product MFMA (ws too small path).
// ---------------------------------------------------------------------------
__device__ __forceinline__ void stage_half(char* __restrict__ hi_base,
                                           char* __restrict__ lo_base,
                                           const float4* cv, const float4* wv,
                                           float s, int r, int h) {
  unsigned hu[16], lu[16];
#pragma unroll
  for (int i = 0; i < 8; ++i) {
    float f[4] = {cv[i].x * wv[i].x * s, cv[i].y * wv[i].y * s,
                  cv[i].z * wv[i].z * s, cv[i].w * wv[i].w * s};
    unsigned hb[4], lb[4];
#pragma unroll
    for (int j = 0; j < 4; ++j) {
      hb[j] = f2bf(f[j]);
      float hf = __uint_as_float(hb[j] << 16);
      lb[j] = f2bf(f[j] - hf);
    }
    hu[2 * i] = hb[0] | (hb[1] << 16);
    hu[2 * i + 1] = hb[2] | (hb[3] << 16);
    lu[2 * i] = lb[0] | (lb[1] << 16);
    lu[2 * i + 1] = lb[2] | (lb[3] << 16);
  }
#pragma unroll
  for (int c = 0; c < 4; ++c) {
    int boff = r * 128 + SWZ(r, h * 64 + c * 16);
    *reinterpret_cast<uint4*>(hi_base + boff) =
        make_uint4(hu[4 * c], hu[4 * c + 1], hu[4 * c + 2], hu[4 * c + 3]);
    *reinterpret_cast<uint4*>(lo_base + boff) =
        make_uint4(lu[4 * c], lu[4 * c + 1], lu[4 * c + 2], lu[4 * c + 3]);
  }
}

__global__ __launch_bounds__(256, 2) void att_gemm(
    const float* __restrict__ ctx, const float* __restrict__ w,
    const float* __restrict__ invr, float* __restrict__ out) {
  const int bx = blockIdx.x, by = blockIdx.y;
  if (by > bx) return;

  __shared__ __align__(16) char Ahi[BM * 128];
  __shared__ __align__(16) char Alo[BM * 128];
  __shared__ __align__(16) char Bhi[BM * 128];
  __shared__ __align__(16) char Blo[BM * 128];

  const int t = threadIdx.x;
  const int lane = t & 63, wid = t >> 6;
  const int wr = wid >> 1, wc = wid & 1;
  const int Ro = by * BM, Co = bx * BM;
  const int srow = t >> 1;
  const int sh = t & 1;

  f32x4 acc[4][4] = {};

  for (int k0 = 0; k0 < KTOT; k0 += BK) {
    const int p = k0 >> 9;
    const int d0 = (k0 & (DIM - 1)) + sh * 32;

    float4 cva[8], cvb[8], wv[8];
    const float* wrow = w + (size_t)p * DIM + d0;
    const float* arow = ctx + (size_t)(Ro + srow) * DIM + d0;
    const float* brow = ctx + (size_t)(Co + srow) * DIM + d0;
#pragma unroll
    for (int i = 0; i < 8; ++i) {
      wv[i] = *reinterpret_cast<const float4*>(wrow + 4 * i);
      cva[i] = *reinterpret_cast<const float4*>(arow + 4 * i);
      cvb[i] = *reinterpret_cast<const float4*>(brow + 4 * i);
    }
    const float sA = invr[(size_t)p * N_CTX + Ro + srow];
    const float sB = invr[(size_t)p * N_CTX + Co + srow];

    __syncthreads();
    stage_half(Ahi, Alo, cva, wv, sA, srow, sh);
    stage_half(Bhi, Blo, cvb, wv, sB, srow, sh);
    __syncthreads();

#pragma unroll
    for (int ks = 0; ks < 2; ++ks) {
      const int kb = ks * 64 + (lane >> 4) * 16;
      bfrag ah[4], al[4], bh[4], bl[4];
#pragma unroll
      for (int m = 0; m < 4; ++m) {
        const int r = wr * 64 + m * 16 + (lane & 15);
        const int off = r * 128 + SWZ(r, kb);
        ah[m] = *reinterpret_cast<const bfrag*>(Ahi + off);
        al[m] = *reinterpret_cast<const bfrag*>(Alo + off);
      }
#pragma unroll
      for (int n = 0; n < 4; ++n) {
        const int r = wc * 64 + n * 16 + (lane & 15);
        const int off = r * 128 + SWZ(r, kb);
        bh[n] = *reinterpret_cast<const bfrag*>(Bhi + off);
        bl[n] = *reinterpret_cast<const bfrag*>(Blo + off);
      }
#pragma unroll
      for (int m = 0; m < 4; ++m)
#pragma unroll
        for (int n = 0; n < 4; ++n) {
          acc[m][n] = __builtin_amdgcn_mfma_f32_16x16x32_bf16(ah[m], bh[n], acc[m][n], 0, 0, 0);
          acc[m][n] = __builtin_amdgcn_mfma_f32_16x16x32_bf16(ah[m], bl[n], acc[m][n], 0, 0, 0);
          acc[m][n] = __builtin_amdgcn_mfma_f32_16x16x32_bf16(al[m], bh[n], acc[m][n], 0, 0, 0);
        }
    }
  }

  const int col = lane & 15, rq = (lane >> 4) * 4;
#pragma unroll
  for (int m = 0; m < 4; ++m)
#pragma unroll
    for (int n = 0; n < 4; ++n) {
      const int gr = Ro + wr * 64 + m * 16 + rq;
      const int gc = Co + wc * 64 + n * 16 + col;
#pragma unroll
      for (int j = 0; j < 4; ++j)
        out[(size_t)(gr + j) * N_CTX + gc] = acc[m][n][j];
      if (bx != by) {
        *reinterpret_cast<float4*>(out + (size_t)gc * N_CTX + gr) =
            make_float4(acc[m][n][0], acc[m][n][1], acc[m][n][2], acc[m][n][3]);
      }
    }
}

// ---------------------------------------------------------------------------
// Kernel 3: scan — UNCHANGED from R17-R20 (stores candV + nearEps flag).
// ---------------------------------------------------------------------------
__global__ __launch_bounds__(256) void topk_scan(
    float* __restrict__ att, int* __restrict__ candM,
    float* __restrict__ candV, int* __restrict__ cnt_g) {
  __shared__ unsigned red[2][4];
  __shared__ int lcnt, lg;

  const int n = blockIdx.x;
  const int t = threadIdx.x;
  const int wid = t >> 6, lane = t & 63;
  float* row = att + (size_t)n * N_CTX;

  float ar[16], tr[16];
  unsigned ur[16];
#pragma unroll
  for (int i = 0; i < 4; ++i) {
    float4 v4 = *reinterpret_cast<const float4*>(row + (size_t)(i * 256 + t) * 4);
    float tmp[4] = {v4.x, v4.y, v4.z, v4.w};
#pragma unroll
    for (int j = 0; j < 4; ++j) {
      float a = tmp[j];
      float tt = (a > EPS_NN) ? a : 0.0f;
      ar[i * 4 + j] = a;
      tr[i * 4 + j] = tt;
      ur[i * 4 + j] = __float_as_uint(tt);
    }
  }
  if (t == 0) { lcnt = 0; lg = 0; }

  unsigned lo = 0u, hi = 0x7F800000u;
  int buf = 0;
  while (lo < hi) {
    unsigned mid = lo + ((hi - lo) >> 1);
    unsigned c = 0;
#pragma unroll
    for (int i = 0; i < 16; ++i) c += (ur[i] > mid) ? 1u : 0u;
#pragma unroll
    for (int off = 32; off; off >>= 1) c += __shfl_down(c, off, 64);
    if (lane == 0) red[buf][wid] = c;
    __syncthreads();
    unsigned tot = red[buf][0] + red[buf][1] + red[buf][2] + red[buf][3];
    if (tot < TOPK_K) hi = mid; else lo = mid + 1;
    buf ^= 1;
  }
  const float vk = __uint_as_float(lo);
  const bool nearEps = (vk <= EPS_NN + 2.0f * DELTA);
  __syncthreads();   // lcnt/lg init visible

  unsigned myg = 0;
#pragma unroll
  for (int i = 0; i < 16; ++i) {
    const int blk = i >> 2, j = i & 3;
    const int m = (blk * 256 + t) * 4 + j;
    const float a = ar[i], tt = tr[i];
    const bool isEps = fabsf(a - EPS_NN) <= DELTA;
    const bool isOrd = (tt > 0.f) && (fabsf(tt - vk) <= DELTA);
    const bool cand = isOrd || (isEps && nearEps);
    const bool defIn = (tt > vk + DELTA) && !cand;
    tr[i] = defIn ? tt : 0.f;
    myg += defIn ? 1u : 0u;
    unsigned long long mask = __ballot(cand);
    if (mask) {
      int base = 0;
      if (lane == 0) base = atomicAdd(&lcnt, (int)__popcll(mask));
      base = __shfl(base, 0, 64);
      if (cand) {
        int pos = base + (int)__popcll(mask & ((1ull << lane) - 1ull));
        if (pos < CAP) {
          candM[n * CAP + pos] = m;
          candV[n * CAP + pos] = tt;
        }
      }
    }
  }
#pragma unroll
  for (int off = 32; off; off >>= 1) myg += __shfl_down(myg, off, 64);
  if (lane == 0) atomicAdd(&lg, (int)myg);

#pragma unroll
  for (int i = 0; i < 4; ++i) {
    *reinterpret_cast<float4*>(row + (size_t)(i * 256 + t) * 4) =
        make_float4(tr[i * 4], tr[i * 4 + 1], tr[i * 4 + 2], tr[i * 4 + 3]);
  }
  __syncthreads();
  if (t == 0) {
    cnt_g[4 * n] = (lcnt < CAP) ? lcnt : CAP;
    cnt_g[4 * n + 1] = lg;
    cnt_g[4 * n + 2] = nearEps ? 1 : 0;
  }
}

// ---------------------------------------------------------------------------
// Kernel 4: repair + select. R21 three-tier:
//  (a) skip-path (R18, validated): c<=slots && !nearEps -> write approx.
//  (b) refined-parallel triage: per candidate, 64-lane coalesced reduction
//      (lane l sums k=p*512+l+64*i, ascending per lane; fixed shfl tree).
//      |refined - chain| ~3e-6 tail; if refined ranking has all gaps
//      > DELTA2=2e-5 (boundary and eps), decision provably equals the
//      chain's; write refined values (diff invisible at 2e-2 threshold).
//  (c) ambiguous rows only: VERBATIM locked serial chain (bit-identical to
//      R2) + select. Operands L1-warm from (b).
// ---------------------------------------------------------------------------
__global__ __launch_bounds__(64) void repair_select(
    const float* __restrict__ ctx, const float* __restrict__ w,
    const float* __restrict__ invr, const int* __restrict__ candM,
    const float* __restrict__ candV, const int* __restrict__ cnt_g,
    float* __restrict__ att) {
  const int n = blockIdx.x;
  const int c = cnt_g[4 * n];
  if (c == 0) return;
  const int slots = TOPK_K - cnt_g[4 * n + 1];
  const int nearEps = cnt_g[4 * n + 2];
  const int j = threadIdx.x;

  if (c <= slots && !nearEps) {   // all candidates selected; approx values OK
    if (j < c) att[(size_t)n * N_CTX + candM[n * CAP + j]] = candV[n * CAP + j];
    return;
  }

  __shared__ float te_s[CAP];
  __shared__ int m_s[CAP];
  __shared__ float rv_s[CAP];    // refined, post-eps
  __shared__ float rr_s[CAP];    // refined, raw
  if (j < c) m_s[j] = candM[n * CAP + j];
  __syncthreads();

  // ---- Phase (b): refined values, wave-parallel per candidate ----
  const float* cn = ctx + (size_t)n * DIM;
  for (int q = 0; q < c; ++q) {
    const int mq = m_s[q];
    const float* cm = ctx + (size_t)mq * DIM;
    float part = 0.f;
    for (int p = 0; p < NPERS; ++p) {
      const float sA = invr[(size_t)p * N_CTX + n];
      const float sB = invr[(size_t)p * N_CTX + mq];
      const float* wp = w + (size_t)p * DIM;
#pragma unroll
      for (int i2 = 0; i2 < 8; ++i2) {
        const int d = j + 64 * i2;      // coalesced: 64 consecutive floats
        const float fa = (cn[d] * wp[d]) * sA;
        const float fb = (cm[d] * wp[d]) * sB;
        part = fmaf(fa, fb, part);
      }
    }
#pragma unroll
    for (int off = 32; off; off >>= 1) part += __shfl_down(part, off, 64);
    if (j == 0) {
      rr_s[q] = part;
      rv_s[q] = (part > EPS_NN) ? part : 0.f;
    }
  }
  __syncthreads();

  // rank refined; ambiguity test
  bool kept = false;
  float rv = 0.f, rr = 0.f;
  if (j < c) {
    rv = rv_s[j];
    rr = rr_s[j];
    const int m = m_s[j];
    int rank = 0;
    for (int i = 0; i < c; ++i) {
      if (i == j) continue;
      rank += ((rv_s[i] > rv) || (rv_s[i] == rv && m_s[i] < m)) ? 1 : 0;
    }
    kept = (rank < slots);
  }
  float mk = (j < c && kept) ? rv : 3.4e38f;        // min kept value
  float mo = (j < c && !kept) ? rv : -3.4e38f;      // max out value
  float ea = (j < c && fabsf(rr - EPS_NN) <= DELTA2) ? 1.f : 0.f;
#pragma unroll
  for (int off = 32; off; off >>= 1) {
    mk = fminf(mk, __shfl_down(mk, off, 64));
    mo = fmaxf(mo, __shfl_down(mo, off, 64));
    ea = fmaxf(ea, __shfl_down(ea, off, 64));
  }
  mk = __shfl(mk, 0, 64);
  mo = __shfl(mo, 0, 64);
  ea = __shfl(ea, 0, 64);
  const bool ambiguous = (mk - mo <= DELTA2) || (ea > 0.f);

  if (!ambiguous) {
    if (j < c && kept) att[(size_t)n * N_CTX + m_s[j]] = rv;
    return;
  }

  // ---- Phase (c): VERBATIM locked chain (bit-identical to R2) + select ----
  float te = -1.f;
  int m = -1;
  if (j < c) {
    m = m_s[j];
    const float4* cn4 = reinterpret_cast<const float4*>(ctx + (size_t)n * DIM);
    const float4* cm4 = reinterpret_cast<const float4*>(ctx + (size_t)m * DIM);
    float e = 0.f;
    for (int p = 0; p < NPERS; ++p) {
      const float sA = invr[(size_t)p * N_CTX + n];
      const float sB = invr[(size_t)p * N_CTX + m];
      const float4* w4 = reinterpret_cast<const float4*>(w + (size_t)p * DIM);
#pragma unroll 4
      for (int q = 0; q < DIM / 4; ++q) {
        const float4 a = cn4[q], b = cm4[q], ww = w4[q];
        e = fmaf((a.x * ww.x) * sA, (b.x * ww.x) * sB, e);
        e = fmaf((a.y * ww.y) * sA, (b.y * ww.y) * sB, e);
        e = fmaf((a.z * ww.z) * sA, (b.z * ww.z) * sB, e);
        e = fmaf((a.w * ww.w) * sA, (b.w * ww.w) * sB, e);
      }
    }
    te = (e > EPS_NN) ? e : 0.f;
  }
  m_s[j] = m;
  te_s[j] = te;
  __syncthreads();
  if (j < c) {
    int rank = 0;
    for (int i = 0; i < c; ++i) {
      if (i == j) continue;
      rank += ((te_s[i] > te) || (te_s[i] == te && m_s[i] < m)) ? 1 : 0;
    }
    if (rank < slots) att[(size_t)n * N_CTX + m] = te;
  }
}

// ---------------------------------------------------------------------------
extern "C" void kernel_launch(void* const* d_in, const int* in_sizes, int n_in,
                              void* d_out, int out_size, void* d_ws, size_t ws_size,
                              hipStream_t stream) {
  const float* ctx = (const float*)d_in[0];   // (4096, 512)
  const float* w   = (const float*)d_in[1];   // (16, 512)
  float* out = (float*)d_out;                 // (4096, 4096)

  // ws: invr 256KB | cnt_g 64KB | candM 1MB | candV 1MB | Fhi 64MB
  const size_t OFF_CNT = 262144;
  const size_t OFF_CAND = OFF_CNT + 65536;
  const size_t OFF_CV = OFF_CAND + 1048576;
  const size_t OFF_FHI = OFF_CV + 1048576;
  const size_t FSZ = (size_t)32 * NKSTEP * CHUNK;       // 67108864
  float* invr = (float*)d_ws;
  int* cnt_g = (int*)((char*)d_ws + OFF_CNT);
  int* candM = (int*)((char*)d_ws + OFF_CAND);
  float* candV = (float*)((char*)d_ws + OFF_CV);
  unsigned short* Fhi = (unsigned short*)((char*)d_ws + OFF_FHI);
  const bool haveF = ws_size >= OFF_FHI + FSZ;

  if (haveF) {
    split_norms_kernel<<<(N_CTX * 64) / 256, 256, 0, stream>>>(ctx, w, invr, Fhi);
    att_gemm_fast<<<528, 256, 0, stream>>>(Fhi, out);
  } else {
    norms_kernel<<<(NPERS * N_CTX) / 4, 256, 0, stream>>>(ctx, w, invr);
    dim3 grid(N_CTX / BM, N_CTX / BM);
    att_gemm<<<grid, 256, 0, stream>>>(ctx, w, invr, out);
  }

  topk_scan<<<N_CTX, 256, 0, stream>>>(out, candM, candV, cnt_g);
  repair_select<<<N_CTX, 64, 0, stream>>>(ctx, w, invr, candM, candV, cnt_g, out);
}

// Round 22
// 506.808 us; speedup vs baseline: 1.3294x; 1.1484x over previous
//
#include <hip/hip_runtime.h>
#include <math.h>
#include <stdint.h>

#define N_CTX 4096
#define DIM 512
#define NPERS 16
#define KTOT (NPERS * DIM)   // 8192
#define EPS_NN 0.1f
#define TOPK_K 30

#define DELTA 4e-4f          // scan ambiguity margin (GEMM-vs-chain, validated)
#define DELTA2 1e-5f         // refined-vs-chain margin (order noise ~4e-7 RMS)
#define CAP 64               // max candidates per row

#define BM 128               // MFMA output tile
#define BK 64                // K-step (bf16 elems)
#define NKSTEP (KTOT / BK)   // 128
#define CHUNK 16384          // bytes per (panel, k-step) LDS image

typedef __attribute__((ext_vector_type(8))) short bfrag;   // 8 bf16 = 4 VGPR
typedef __attribute__((ext_vector_type(4))) float f32x4;

// round-to-nearest-even float -> bf16 bits
__device__ __forceinline__ unsigned short f2bf(float f) {
  unsigned u = __float_as_uint(f);
  unsigned r = u + 0x7FFFu + ((u >> 16) & 1u);
  return (unsigned short)(r >> 16);
}

#define SWZ(r, b) ((b) ^ (((r) & 7) << 4))

// stage 1 KB: 64 lanes x 16 B. ldst = wave-uniform LDS base; HW adds lane*16.
__device__ __forceinline__ void stage1k(const char* gsrc, char* ldst, int lane) {
#if __has_builtin(__builtin_amdgcn_global_load_lds)
  __builtin_amdgcn_global_load_lds(
      (const __attribute__((address_space(1))) unsigned int*)(uintptr_t)(gsrc + lane * 16),
      (__attribute__((address_space(3))) unsigned int*)(uintptr_t)ldst, 16, 0, 0);
#else
  *reinterpret_cast<uint4*>(ldst + lane * 16) =
      *reinterpret_cast<const uint4*>(gsrc + lane * 16);
#endif
}

// ---------------------------------------------------------------------------
// Kernel 1 (fallback only): invr[p][n] = 0.25 / max(||c_n * w_p||, 1e-12)
// ---------------------------------------------------------------------------
__global__ __launch_bounds__(256) void norms_kernel(
    const float* __restrict__ ctx, const float* __restrict__ w,
    float* __restrict__ invr) {
  int wid = threadIdx.x >> 6;
  int lane = threadIdx.x & 63;
  int gid = blockIdx.x * 4 + wid;          // 0 .. 65535
  int p = gid >> 12;
  int n = gid & (N_CTX - 1);
  const float4* c4 = reinterpret_cast<const float4*>(ctx + (size_t)n * DIM + lane * 8);
  const float4* w4 = reinterpret_cast<const float4*>(w + (size_t)p * DIM + lane * 8);
  float4 c0 = c4[0], c1 = c4[1];
  float4 w0 = w4[0], w1 = w4[1];
  float s = 0.f, v;
  v = c0.x * w0.x; s = fmaf(v, v, s);
  v = c0.y * w0.y; s = fmaf(v, v, s);
  v = c0.z * w0.z; s = fmaf(v, v, s);
  v = c0.w * w0.w; s = fmaf(v, v, s);
  v = c1.x * w1.x; s = fmaf(v, v, s);
  v = c1.y * w1.y; s = fmaf(v, v, s);
  v = c1.z * w1.z; s = fmaf(v, v, s);
  v = c1.w * w1.w; s = fmaf(v, v, s);
#pragma unroll
  for (int off = 32; off; off >>= 1) s += __shfl_down(s, off, 64);
  if (lane == 0) invr[(size_t)p * N_CTX + n] = 0.25f / fmaxf(sqrtf(s), 1e-12f);
}

// ---------------------------------------------------------------------------
// Kernel 1+1b FUSED: norms (bit-identical chain) + bf16-hi split into the
// panel-swizzled LDS-image layout. UNCHANGED from R16-R21.
// ---------------------------------------------------------------------------
__global__ __launch_bounds__(256) void split_norms_kernel(
    const float* __restrict__ ctx, const float* __restrict__ w,
    float* __restrict__ invr, unsigned short* __restrict__ Fhi) {
  const int tid = blockIdx.x * 256 + threadIdx.x;   // 0 .. 4096*64-1
  const int n = tid >> 6;                 // wave-uniform (wave = 64 aligned)
  const int db = tid & 63;                // lane = 8-col block within 512-dim
  const int d0 = db * 8;
  const int P = n >> 7;                   // panel
  const int r = n & 127;                  // row within panel
  const int sl = db & 7;                  // 16B slot within k-step chunk
  const int swzoff = r * 128 + ((sl * 16) ^ ((r & 7) << 4));

  const float4 c0 = *reinterpret_cast<const float4*>(ctx + (size_t)n * DIM + d0);
  const float4 c1 = *reinterpret_cast<const float4*>(ctx + (size_t)n * DIM + d0 + 4);

#pragma unroll
  for (int p = 0; p < NPERS; ++p) {
    const float4 w0 = *reinterpret_cast<const float4*>(w + (size_t)p * DIM + d0);
    const float4 w1 = *reinterpret_cast<const float4*>(w + (size_t)p * DIM + d0 + 4);

    float pr[8] = {c0.x * w0.x, c0.y * w0.y, c0.z * w0.z, c0.w * w0.w,
                   c1.x * w1.x, c1.y * w1.y, c1.z * w1.z, c1.w * w1.w};

    float s = 0.f;
#pragma unroll
    for (int j = 0; j < 8; ++j) s = fmaf(pr[j], pr[j], s);
#pragma unroll
    for (int off = 32; off; off >>= 1) s += __shfl_down(s, off, 64);
    const float stot = __shfl(s, 0, 64);
    const float sc = 0.25f / fmaxf(sqrtf(stot), 1e-12f);
    if (db == 0) invr[(size_t)p * N_CTX + n] = sc;

    unsigned hb[8];
#pragma unroll
    for (int j = 0; j < 8; ++j) hb[j] = f2bf(pr[j] * sc);   // == (c*w)*sc
    uint4 hv = make_uint4(hb[0] | (hb[1] << 16), hb[2] | (hb[3] << 16),
                          hb[4] | (hb[5] << 16), hb[6] | (hb[7] << 16));
    const int kstep = p * 8 + (db >> 3);           // k-step index
    const size_t base = (size_t)(P * 128 + kstep) * CHUNK + swzoff;
    *reinterpret_cast<uint4*>((char*)Fhi + base) = hv;
  }
}

// ---------------------------------------------------------------------------
// Kernel 2 (fast): att ~= Fhi Fhi^T via bf16 MFMA, SINGLE product.
// UNCHANGED from R16 (validated).
// ---------------------------------------------------------------------------
__global__ __launch_bounds__(256, 3) void att_gemm_fast(
    const unsigned short* __restrict__ Fhi, float* __restrict__ out) {
  const int bid0 = blockIdx.x;
  int bid = (bid0 & 7) * 66 + (bid0 >> 3);   // XCD-contiguous tile runs
  int by = 0;
  while (bid >= (by + 1) * 32 - ((by + 1) * by) / 2) ++by;
  const int bx = by + (bid - (by * 32 - (by * (by - 1)) / 2));

  __shared__ __align__(16) char Ahi[CHUNK];
  __shared__ __align__(16) char Bhi[CHUNK];

  const int t = threadIdx.x;
  const int lane = t & 63, wid = t >> 6;
  const int wr = wid >> 1, wc = wid & 1;
  const int woff = __builtin_amdgcn_readfirstlane(wid * 4096);

  const char* gAh = (const char*)Fhi + (size_t)by * NKSTEP * CHUNK + woff;
  const char* gBh = (const char*)Fhi + (size_t)bx * NKSTEP * CHUNK + woff;

  f32x4 acc[4][4] = {};

  for (int s = 0; s < NKSTEP; ++s) {
    const size_t so = (size_t)s * CHUNK;
#pragma unroll
    for (int i = 0; i < 4; ++i) {
      stage1k(gAh + so + i * 1024, Ahi + woff + i * 1024, lane);
      stage1k(gBh + so + i * 1024, Bhi + woff + i * 1024, lane);
    }
    __syncthreads();

#pragma unroll
    for (int ks = 0; ks < 2; ++ks) {
      const int kb = ks * 64 + (lane >> 4) * 16;
      bfrag ah[4], bh[4];
#pragma unroll
      for (int m = 0; m < 4; ++m) {
        const int r = wr * 64 + m * 16 + (lane & 15);
        ah[m] = *reinterpret_cast<const bfrag*>(Ahi + r * 128 + SWZ(r, kb));
      }
#pragma unroll
      for (int n2 = 0; n2 < 4; ++n2) {
        const int r = wc * 64 + n2 * 16 + (lane & 15);
        bh[n2] = *reinterpret_cast<const bfrag*>(Bhi + r * 128 + SWZ(r, kb));
      }
#pragma unroll
      for (int m = 0; m < 4; ++m)
#pragma unroll
        for (int n2 = 0; n2 < 4; ++n2)
          acc[m][n2] = __builtin_amdgcn_mfma_f32_16x16x32_bf16(ah[m], bh[n2], acc[m][n2], 0, 0, 0);
    }
    __syncthreads();
  }

  const int Ro = by * BM, Co = bx * BM;
  const int col = lane & 15, rq = (lane >> 4) * 4;
#pragma unroll
  for (int m = 0; m < 4; ++m)
#pragma unroll
    for (int n2 = 0; n2 < 4; ++n2) {
      const int gr = Ro + wr * 64 + m * 16 + rq;
      const int gc = Co + wc * 64 + n2 * 16 + col;
#pragma unroll
      for (int j = 0; j < 4; ++j)
        out[(size_t)(gr + j) * N_CTX + gc] = acc[m][n2][j];
      if (bx != by) {
        *reinterpret_cast<float4*>(out + (size_t)gc * N_CTX + gr) =
            make_float4(acc[m][n2][0], acc[m][n2][1], acc[m][n2][2], acc[m][n2][3]);
      }
    }
}

// ---------------------------------------------------------------------------
// Kernel 2 (fallback): on-the-fly split + 3-product MFMA (ws too small path).
// ---------------------------------------------------------------------------
__device__ __forceinline__ void stage_half(char* __restrict__ hi_base,
                                           char* __restrict__ lo_base,
                                           const float4* cv, const float4* wv,
                                           float s, int r, int h) {
  unsigned hu[16], lu[16];
#pragma unroll
  for (int i = 0; i < 8; ++i) {
    float f[4] = {cv[i].x * wv[i].x * s, cv[i].y * wv[i].y * s,
                  cv[i].z * wv[i].z * s, cv[i].w * wv[i].w * s};
    unsigned hb[4], lb[4];
#pragma unroll
    for (int j = 0; j < 4; ++j) {
      hb[j] = f2bf(f[j]);
      float hf = __uint_as_float(hb[j] << 16);
      lb[j] = f2bf(f[j] - hf);
    }
    hu[2 * i] = hb[0] | (hb[1] << 16);
    hu[2 * i + 1] = hb[2] | (hb[3] << 16);
    lu[2 * i] = lb[0] | (lb[1] << 16);
    lu[2 * i + 1] = lb[2] | (lb[3] << 16);
  }
#pragma unroll
  for (int c = 0; c < 4; ++c) {
    int boff = r * 128 + SWZ(r, h * 64 + c * 16);
    *reinterpret_cast<uint4*>(hi_base + boff) =
        make_uint4(hu[4 * c], hu[4 * c + 1], hu[4 * c + 2], hu[4 * c + 3]);
    *reinterpret_cast<uint4*>(lo_base + boff) =
        make_uint4(lu[4 * c], lu[4 * c + 1], lu[4 * c + 2], lu[4 * c + 3]);
  }
}

__global__ __launch_bounds__(256, 2) void att_gemm(
    const float* __restrict__ ctx, const float* __restrict__ w,
    const float* __restrict__ invr, float* __restrict__ out) {
  const int bx = blockIdx.x, by = blockIdx.y;
  if (by > bx) return;

  __shared__ __align__(16) char Ahi[BM * 128];
  __shared__ __align__(16) char Alo[BM * 128];
  __shared__ __align__(16) char Bhi[BM * 128];
  __shared__ __align__(16) char Blo[BM * 128];

  const int t = threadIdx.x;
  const int lane = t & 63, wid = t >> 6;
  const int wr = wid >> 1, wc = wid & 1;
  const int Ro = by * BM, Co = bx * BM;
  const int srow = t >> 1;
  const int sh = t & 1;

  f32x4 acc[4][4] = {};

  for (int k0 = 0; k0 < KTOT; k0 += BK) {
    const int p = k0 >> 9;
    const int d0 = (k0 & (DIM - 1)) + sh * 32;

    float4 cva[8], cvb[8], wv[8];
    const float* wrow = w + (size_t)p * DIM + d0;
    const float* arow = ctx + (size_t)(Ro + srow) * DIM + d0;
    const float* brow = ctx + (size_t)(Co + srow) * DIM + d0;
#pragma unroll
    for (int i = 0; i < 8; ++i) {
      wv[i] = *reinterpret_cast<const float4*>(wrow + 4 * i);
      cva[i] = *reinterpret_cast<const float4*>(arow + 4 * i);
      cvb[i] = *reinterpret_cast<const float4*>(brow + 4 * i);
    }
    const float sA = invr[(size_t)p * N_CTX + Ro + srow];
    const float sB = invr[(size_t)p * N_CTX + Co + srow];

    __syncthreads();
    stage_half(Ahi, Alo, cva, wv, sA, srow, sh);
    stage_half(Bhi, Blo, cvb, wv, sB, srow, sh);
    __syncthreads();

#pragma unroll
    for (int ks = 0; ks < 2; ++ks) {
      const int kb = ks * 64 + (lane >> 4) * 16;
      bfrag ah[4], al[4], bh[4], bl[4];
#pragma unroll
      for (int m = 0; m < 4; ++m) {
        const int r = wr * 64 + m * 16 + (lane & 15);
        const int off = r * 128 + SWZ(r, kb);
        ah[m] = *reinterpret_cast<const bfrag*>(Ahi + off);
        al[m] = *reinterpret_cast<const bfrag*>(Alo + off);
      }
#pragma unroll
      for (int n = 0; n < 4; ++n) {
        const int r = wc * 64 + n * 16 + (lane & 15);
        const int off = r * 128 + SWZ(r, kb);
        bh[n] = *reinterpret_cast<const bfrag*>(Bhi + off);
        bl[n] = *reinterpret_cast<const bfrag*>(Blo + off);
      }
#pragma unroll
      for (int m = 0; m < 4; ++m)
#pragma unroll
        for (int n = 0; n < 4; ++n) {
          acc[m][n] = __builtin_amdgcn_mfma_f32_16x16x32_bf16(ah[m], bh[n], acc[m][n], 0, 0, 0);
          acc[m][n] = __builtin_amdgcn_mfma_f32_16x16x32_bf16(ah[m], bl[n], acc[m][n], 0, 0, 0);
          acc[m][n] = __builtin_amdgcn_mfma_f32_16x16x32_bf16(al[m], bh[n], acc[m][n], 0, 0, 0);
        }
    }
  }

  const int col = lane & 15, rq = (lane >> 4) * 4;
#pragma unroll
  for (int m = 0; m < 4; ++m)
#pragma unroll
    for (int n = 0; n < 4; ++n) {
      const int gr = Ro + wr * 64 + m * 16 + rq;
      const int gc = Co + wc * 64 + n * 16 + col;
#pragma unroll
      for (int j = 0; j < 4; ++j)
        out[(size_t)(gr + j) * N_CTX + gc] = acc[m][n][j];
      if (bx != by) {
        *reinterpret_cast<float4*>(out + (size_t)gc * N_CTX + gr) =
            make_float4(acc[m][n][0], acc[m][n][1], acc[m][n][2], acc[m][n][3]);
      }
    }
}

// ---------------------------------------------------------------------------
// Kernel 3: scan — UNCHANGED from R17-R21 (stores candV + nearEps flag).
// ---------------------------------------------------------------------------
__global__ __launch_bounds__(256) void topk_scan(
    float* __restrict__ att, int* __restrict__ candM,
    float* __restrict__ candV, int* __restrict__ cnt_g) {
  __shared__ unsigned red[2][4];
  __shared__ int lcnt, lg;

  const int n = blockIdx.x;
  const int t = threadIdx.x;
  const int wid = t >> 6, lane = t & 63;
  float* row = att + (size_t)n * N_CTX;

  float ar[16], tr[16];
  unsigned ur[16];
#pragma unroll
  for (int i = 0; i < 4; ++i) {
    float4 v4 = *reinterpret_cast<const float4*>(row + (size_t)(i * 256 + t) * 4);
    float tmp[4] = {v4.x, v4.y, v4.z, v4.w};
#pragma unroll
    for (int j = 0; j < 4; ++j) {
      float a = tmp[j];
      float tt = (a > EPS_NN) ? a : 0.0f;
      ar[i * 4 + j] = a;
      tr[i * 4 + j] = tt;
      ur[i * 4 + j] = __float_as_uint(tt);
    }
  }
  if (t == 0) { lcnt = 0; lg = 0; }

  unsigned lo = 0u, hi = 0x7F800000u;
  int buf = 0;
  while (lo < hi) {
    unsigned mid = lo + ((hi - lo) >> 1);
    unsigned c = 0;
#pragma unroll
    for (int i = 0; i < 16; ++i) c += (ur[i] > mid) ? 1u : 0u;
#pragma unroll
    for (int off = 32; off; off >>= 1) c += __shfl_down(c, off, 64);
    if (lane == 0) red[buf][wid] = c;
    __syncthreads();
    unsigned tot = red[buf][0] + red[buf][1] + red[buf][2] + red[buf][3];
    if (tot < TOPK_K) hi = mid; else lo = mid + 1;
    buf ^= 1;
  }
  const float vk = __uint_as_float(lo);
  const bool nearEps = (vk <= EPS_NN + 2.0f * DELTA);
  __syncthreads();   // lcnt/lg init visible

  unsigned myg = 0;
#pragma unroll
  for (int i = 0; i < 16; ++i) {
    const int blk = i >> 2, j = i & 3;
    const int m = (blk * 256 + t) * 4 + j;
    const float a = ar[i], tt = tr[i];
    const bool isEps = fabsf(a - EPS_NN) <= DELTA;
    const bool isOrd = (tt > 0.f) && (fabsf(tt - vk) <= DELTA);
    const bool cand = isOrd || (isEps && nearEps);
    const bool defIn = (tt > vk + DELTA) && !cand;
    tr[i] = defIn ? tt : 0.f;
    myg += defIn ? 1u : 0u;
    unsigned long long mask = __ballot(cand);
    if (mask) {
      int base = 0;
      if (lane == 0) base = atomicAdd(&lcnt, (int)__popcll(mask));
      base = __shfl(base, 0, 64);
      if (cand) {
        int pos = base + (int)__popcll(mask & ((1ull << lane) - 1ull));
        if (pos < CAP) {
          candM[n * CAP + pos] = m;
          candV[n * CAP + pos] = tt;
        }
      }
    }
  }
#pragma unroll
  for (int off = 32; off; off >>= 1) myg += __shfl_down(myg, off, 64);
  if (lane == 0) atomicAdd(&lg, (int)myg);

#pragma unroll
  for (int i = 0; i < 4; ++i) {
    *reinterpret_cast<float4*>(row + (size_t)(i * 256 + t) * 4) =
        make_float4(tr[i * 4], tr[i * 4 + 1], tr[i * 4 + 2], tr[i * 4 + 3]);
  }
  __syncthreads();
  if (t == 0) {
    cnt_g[4 * n] = (lcnt < CAP) ? lcnt : CAP;
    cnt_g[4 * n + 1] = lg;
    cnt_g[4 * n + 2] = nearEps ? 1 : 0;
  }
}

// ---------------------------------------------------------------------------
// Kernel 4: repair + select. R22:
//  (a) skip-path (validated).
//  (b) refined triage with 8 INDEPENDENT accumulators (8x load ILP;
//      deterministic; order-noise ~4e-7 RMS vs chain).
//  (c) ambiguous rows only (DELTA2=1e-5): VERBATIM locked chain
//      (invr scalars hoisted — identical values, same fmaf order ->
//      bit-identical) + select.
// ---------------------------------------------------------------------------
__global__ __launch_bounds__(64) void repair_select(
    const float* __restrict__ ctx, const float* __restrict__ w,
    const float* __restrict__ invr, const int* __restrict__ candM,
    const float* __restrict__ candV, const int* __restrict__ cnt_g,
    float* __restrict__ att) {
  const int n = blockIdx.x;
  const int c = cnt_g[4 * n];
  if (c == 0) return;
  const int slots = TOPK_K - cnt_g[4 * n + 1];
  const int nearEps = cnt_g[4 * n + 2];
  const int j = threadIdx.x;

  if (c <= slots && !nearEps) {   // all candidates selected; approx values OK
    if (j < c) att[(size_t)n * N_CTX + candM[n * CAP + j]] = candV[n * CAP + j];
    return;
  }

  __shared__ float te_s[CAP];
  __shared__ int m_s[CAP];
  __shared__ float rv_s[CAP];    // refined, post-eps
  __shared__ float rr_s[CAP];    // refined, raw
  if (j < c) m_s[j] = candM[n * CAP + j];
  __syncthreads();

  // ---- Phase (b): refined values, wave-parallel, 8 independent accums ----
  const float* cn = ctx + (size_t)n * DIM;
  for (int q = 0; q < c; ++q) {
    const int mq = m_s[q];
    const float* cm = ctx + (size_t)mq * DIM;
    float acc8[8] = {0.f, 0.f, 0.f, 0.f, 0.f, 0.f, 0.f, 0.f};
    for (int p = 0; p < NPERS; ++p) {
      const float sA = invr[(size_t)p * N_CTX + n];
      const float sB = invr[(size_t)p * N_CTX + mq];
      const float* wp = w + (size_t)p * DIM;
#pragma unroll
      for (int i2 = 0; i2 < 8; ++i2) {
        const int d = j + 64 * i2;      // coalesced: 64 consecutive floats
        const float fa = (cn[d] * wp[d]) * sA;
        const float fb = (cm[d] * wp[d]) * sB;
        acc8[i2] = fmaf(fa, fb, acc8[i2]);
      }
    }
    float part = ((acc8[0] + acc8[1]) + (acc8[2] + acc8[3])) +
                 ((acc8[4] + acc8[5]) + (acc8[6] + acc8[7]));
#pragma unroll
    for (int off = 32; off; off >>= 1) part += __shfl_down(part, off, 64);
    if (j == 0) {
      rr_s[q] = part;
      rv_s[q] = (part > EPS_NN) ? part : 0.f;
    }
  }
  __syncthreads();

  // rank refined; ambiguity test
  bool kept = false;
  float rv = 0.f, rr = 0.f;
  if (j < c) {
    rv = rv_s[j];
    rr = rr_s[j];
    const int m = m_s[j];
    int rank = 0;
    for (int i = 0; i < c; ++i) {
      if (i == j) continue;
      rank += ((rv_s[i] > rv) || (rv_s[i] == rv && m_s[i] < m)) ? 1 : 0;
    }
    kept = (rank < slots);
  }
  float mk = (j < c && kept) ? rv : 3.4e38f;        // min kept value
  float mo = (j < c && !kept) ? rv : -3.4e38f;      // max out value
  float ea = (j < c && fabsf(rr - EPS_NN) <= DELTA2) ? 1.f : 0.f;
#pragma unroll
  for (int off = 32; off; off >>= 1) {
    mk = fminf(mk, __shfl_down(mk, off, 64));
    mo = fmaxf(mo, __shfl_down(mo, off, 64));
    ea = fmaxf(ea, __shfl_down(ea, off, 64));
  }
  mk = __shfl(mk, 0, 64);
  mo = __shfl(mo, 0, 64);
  ea = __shfl(ea, 0, 64);
  const bool ambiguous = (mk - mo <= DELTA2) || (ea > 0.f);

  if (!ambiguous) {
    if (j < c && kept) att[(size_t)n * N_CTX + m_s[j]] = rv;
    return;
  }

  // ---- Phase (c): VERBATIM locked chain (bit-identical to R2) + select ----
  float te = -1.f;
  int m = -1;
  if (j < c) {
    m = m_s[j];
    const float4* cn4 = reinterpret_cast<const float4*>(ctx + (size_t)n * DIM);
    const float4* cm4 = reinterpret_cast<const float4*>(ctx + (size_t)m * DIM);
    float sAv[NPERS], sBv[NPERS];
#pragma unroll
    for (int p = 0; p < NPERS; ++p) {
      sAv[p] = invr[(size_t)p * N_CTX + n];
      sBv[p] = invr[(size_t)p * N_CTX + m];
    }
    float e = 0.f;
#pragma unroll 1
    for (int p = 0; p < NPERS; ++p) {
      const float sA = sAv[p];
      const float sB = sBv[p];
      const float4* w4 = reinterpret_cast<const float4*>(w + (size_t)p * DIM);
#pragma unroll 8
      for (int q = 0; q < DIM / 4; ++q) {
        const float4 a = cn4[q], b = cm4[q], ww = w4[q];
        e = fmaf((a.x * ww.x) * sA, (b.x * ww.x) * sB, e);
        e = fmaf((a.y * ww.y) * sA, (b.y * ww.y) * sB, e);
        e = fmaf((a.z * ww.z) * sA, (b.z * ww.z) * sB, e);
        e = fmaf((a.w * ww.w) * sA, (b.w * ww.w) * sB, e);
      }
    }
    te = (e > EPS_NN) ? e : 0.f;
  }
  m_s[j] = m;
  te_s[j] = te;
  __syncthreads();
  if (j < c) {
    int rank = 0;
    for (int i = 0; i < c; ++i) {
      if (i == j) continue;
      rank += ((te_s[i] > te) || (te_s[i] == te && m_s[i] < m)) ? 1 : 0;
    }
    if (rank < slots) att[(size_t)n * N_CTX + m] = te;
  }
}

// ---------------------------------------------------------------------------
extern "C" void kernel_launch(void* const* d_in, const int* in_sizes, int n_in,
                              void* d_out, int out_size, void* d_ws, size_t ws_size,
                              hipStream_t stream) {
  const float* ctx = (const float*)d_in[0];   // (4096, 512)
  const float* w   = (const float*)d_in[1];   // (16, 512)
  float* out = (float*)d_out;                 // (4096, 4096)

  // ws: invr 256KB | cnt_g 64KB | candM 1MB | candV 1MB | Fhi 64MB
  const size_t OFF_CNT = 262144;
  const size_t OFF_CAND = OFF_CNT + 65536;
  const size_t OFF_CV = OFF_CAND + 1048576;
  const size_t OFF_FHI = OFF_CV + 1048576;
  const size_t FSZ = (size_t)32 * NKSTEP * CHUNK;       // 67108864
  float* invr = (float*)d_ws;
  int* cnt_g = (int*)((char*)d_ws + OFF_CNT);
  int* candM = (int*)((char*)d_ws + OFF_CAND);
  float* candV = (float*)((char*)d_ws + OFF_CV);
  unsigned short* Fhi = (unsigned short*)((char*)d_ws + OFF_FHI);
  const bool haveF = ws_size >= OFF_FHI + FSZ;

  if (haveF) {
    split_norms_kernel<<<(N_CTX * 64) / 256, 256, 0, stream>>>(ctx, w, invr, Fhi);
    att_gemm_fast<<<528, 256, 0, stream>>>(Fhi, out);
  } else {
    norms_kernel<<<(NPERS * N_CTX) / 4, 256, 0, stream>>>(ctx, w, invr);
    dim3 grid(N_CTX / BM, N_CTX / BM);
    att_gemm<<<grid, 256, 0, stream>>>(ctx, w, invr, out);
  }

  topk_scan<<<N_CTX, 256, 0, stream>>>(out, candM, candV, cnt_g);
  repair_select<<<N_CTX, 64, 0, stream>>>(ctx, w, invr, candM, candV, cnt_g, out);
}

// Round 23
// 409.583 us; speedup vs baseline: 1.6450x; 1.2374x over previous
//
#include <hip/hip_runtime.h>
#include <math.h>
#include <stdint.h>

#define N_CTX 4096
#define DIM 512
#define NPERS 16
#define KTOT (NPERS * DIM)   // 8192
#define EPS_NN 0.1f
#define TOPK_K 30

#define DELTA 4e-4f          // scan ambiguity margin (GEMM-vs-chain, validated)
#define DELTA2 1e-5f         // refined-vs-chain margin (order noise ~4e-7 RMS)
#define CAP 64               // max candidates per row
#define CAPL 12              // cm rows staged in LDS (c>CAPL lanes use global)

#define BM 128               // MFMA output tile
#define BK 64                // K-step (bf16 elems)
#define NKSTEP (KTOT / BK)   // 128
#define CHUNK 16384          // bytes per (panel, k-step) LDS image

typedef __attribute__((ext_vector_type(8))) short bfrag;   // 8 bf16 = 4 VGPR
typedef __attribute__((ext_vector_type(4))) float f32x4;

// round-to-nearest-even float -> bf16 bits
__device__ __forceinline__ unsigned short f2bf(float f) {
  unsigned u = __float_as_uint(f);
  unsigned r = u + 0x7FFFu + ((u >> 16) & 1u);
  return (unsigned short)(r >> 16);
}

#define SWZ(r, b) ((b) ^ (((r) & 7) << 4))

// stage 1 KB: 64 lanes x 16 B. ldst = wave-uniform LDS base; HW adds lane*16.
__device__ __forceinline__ void stage1k(const char* gsrc, char* ldst, int lane) {
#if __has_builtin(__builtin_amdgcn_global_load_lds)
  __builtin_amdgcn_global_load_lds(
      (const __attribute__((address_space(1))) unsigned int*)(uintptr_t)(gsrc + lane * 16),
      (__attribute__((address_space(3))) unsigned int*)(uintptr_t)ldst, 16, 0, 0);
#else
  *reinterpret_cast<uint4*>(ldst + lane * 16) =
      *reinterpret_cast<const uint4*>(gsrc + lane * 16);
#endif
}

// ---------------------------------------------------------------------------
// Kernel 1 (fallback only): invr[p][n] = 0.25 / max(||c_n * w_p||, 1e-12)
// ---------------------------------------------------------------------------
__global__ __launch_bounds__(256) void norms_kernel(
    const float* __restrict__ ctx, const float* __restrict__ w,
    float* __restrict__ invr, int* __restrict__ gcount) {
  int wid = threadIdx.x >> 6;
  int lane = threadIdx.x & 63;
  int gid = blockIdx.x * 4 + wid;          // 0 .. 65535
  if (blockIdx.x == 0 && threadIdx.x == 0) gcount[0] = 0;
  int p = gid >> 12;
  int n = gid & (N_CTX - 1);
  const float4* c4 = reinterpret_cast<const float4*>(ctx + (size_t)n * DIM + lane * 8);
  const float4* w4 = reinterpret_cast<const float4*>(w + (size_t)p * DIM + lane * 8);
  float4 c0 = c4[0], c1 = c4[1];
  float4 w0 = w4[0], w1 = w4[1];
  float s = 0.f, v;
  v = c0.x * w0.x; s = fmaf(v, v, s);
  v = c0.y * w0.y; s = fmaf(v, v, s);
  v = c0.z * w0.z; s = fmaf(v, v, s);
  v = c0.w * w0.w; s = fmaf(v, v, s);
  v = c1.x * w1.x; s = fmaf(v, v, s);
  v = c1.y * w1.y; s = fmaf(v, v, s);
  v = c1.z * w1.z; s = fmaf(v, v, s);
  v = c1.w * w1.w; s = fmaf(v, v, s);
#pragma unroll
  for (int off = 32; off; off >>= 1) s += __shfl_down(s, off, 64);
  if (lane == 0) invr[(size_t)p * N_CTX + n] = 0.25f / fmaxf(sqrtf(s), 1e-12f);
}

// ---------------------------------------------------------------------------
// Kernel 1+1b FUSED: norms (bit-identical chain) + bf16-hi split into the
// panel-swizzled LDS-image layout. UNCHANGED except gcount zeroing.
// ---------------------------------------------------------------------------
__global__ __launch_bounds__(256) void split_norms_kernel(
    const float* __restrict__ ctx, const float* __restrict__ w,
    float* __restrict__ invr, unsigned short* __restrict__ Fhi,
    int* __restrict__ gcount) {
  const int tid = blockIdx.x * 256 + threadIdx.x;   // 0 .. 4096*64-1
  if (tid == 0) gcount[0] = 0;
  const int n = tid >> 6;                 // wave-uniform (wave = 64 aligned)
  const int db = tid & 63;                // lane = 8-col block within 512-dim
  const int d0 = db * 8;
  const int P = n >> 7;                   // panel
  const int r = n & 127;                  // row within panel
  const int sl = db & 7;                  // 16B slot within k-step chunk
  const int swzoff = r * 128 + ((sl * 16) ^ ((r & 7) << 4));

  const float4 c0 = *reinterpret_cast<const float4*>(ctx + (size_t)n * DIM + d0);
  const float4 c1 = *reinterpret_cast<const float4*>(ctx + (size_t)n * DIM + d0 + 4);

#pragma unroll
  for (int p = 0; p < NPERS; ++p) {
    const float4 w0 = *reinterpret_cast<const float4*>(w + (size_t)p * DIM + d0);
    const float4 w1 = *reinterpret_cast<const float4*>(w + (size_t)p * DIM + d0 + 4);

    float pr[8] = {c0.x * w0.x, c0.y * w0.y, c0.z * w0.z, c0.w * w0.w,
                   c1.x * w1.x, c1.y * w1.y, c1.z * w1.z, c1.w * w1.w};

    float s = 0.f;
#pragma unroll
    for (int j = 0; j < 8; ++j) s = fmaf(pr[j], pr[j], s);
#pragma unroll
    for (int off = 32; off; off >>= 1) s += __shfl_down(s, off, 64);
    const float stot = __shfl(s, 0, 64);
    const float sc = 0.25f / fmaxf(sqrtf(stot), 1e-12f);
    if (db == 0) invr[(size_t)p * N_CTX + n] = sc;

    unsigned hb[8];
#pragma unroll
    for (int j = 0; j < 8; ++j) hb[j] = f2bf(pr[j] * sc);   // == (c*w)*sc
    uint4 hv = make_uint4(hb[0] | (hb[1] << 16), hb[2] | (hb[3] << 16),
                          hb[4] | (hb[5] << 16), hb[6] | (hb[7] << 16));
    const int kstep = p * 8 + (db >> 3);           // k-step index
    const size_t base = (size_t)(P * 128 + kstep) * CHUNK + swzoff;
    *reinterpret_cast<uint4*>((char*)Fhi + base) = hv;
  }
}

// ---------------------------------------------------------------------------
// Kernel 2 (fast): att ~= Fhi Fhi^T via bf16 MFMA, SINGLE product.
// UNCHANGED from R16 (validated).
// ---------------------------------------------------------------------------
__global__ __launch_bounds__(256, 3) void att_gemm_fast(
    const unsigned short* __restrict__ Fhi, float* __restrict__ out) {
  const int bid0 = blockIdx.x;
  int bid = (bid0 & 7) * 66 + (bid0 >> 3);   // XCD-contiguous tile runs
  int by = 0;
  while (bid >= (by + 1) * 32 - ((by + 1) * by) / 2) ++by;
  const int bx = by + (bid - (by * 32 - (by * (by - 1)) / 2));

  __shared__ __align__(16) char Ahi[CHUNK];
  __shared__ __align__(16) char Bhi[CHUNK];

  const int t = threadIdx.x;
  const int lane = t & 63, wid = t >> 6;
  const int wr = wid >> 1, wc = wid & 1;
  const int woff = __builtin_amdgcn_readfirstlane(wid * 4096);

  const char* gAh = (const char*)Fhi + (size_t)by * NKSTEP * CHUNK + woff;
  const char* gBh = (const char*)Fhi + (size_t)bx * NKSTEP * CHUNK + woff;

  f32x4 acc[4][4] = {};

  for (int s = 0; s < NKSTEP; ++s) {
    const size_t so = (size_t)s * CHUNK;
#pragma unroll
    for (int i = 0; i < 4; ++i) {
      stage1k(gAh + so + i * 1024, Ahi + woff + i * 1024, lane);
      stage1k(gBh + so + i * 1024, Bhi + woff + i * 1024, lane);
    }
    __syncthreads();

#pragma unroll
    for (int ks = 0; ks < 2; ++ks) {
      const int kb = ks * 64 + (lane >> 4) * 16;
      bfrag ah[4], bh[4];
#pragma unroll
      for (int m = 0; m < 4; ++m) {
        const int r = wr * 64 + m * 16 + (lane & 15);
        ah[m] = *reinterpret_cast<const bfrag*>(Ahi + r * 128 + SWZ(r, kb));
      }
#pragma unroll
      for (int n2 = 0; n2 < 4; ++n2) {
        const int r = wc * 64 + n2 * 16 + (lane & 15);
        bh[n2] = *reinterpret_cast<const bfrag*>(Bhi + r * 128 + SWZ(r, kb));
      }
#pragma unroll
      for (int m = 0; m < 4; ++m)
#pragma unroll
        for (int n2 = 0; n2 < 4; ++n2)
          acc[m][n2] = __builtin_amdgcn_mfma_f32_16x16x32_bf16(ah[m], bh[n2], acc[m][n2], 0, 0, 0);
    }
    __syncthreads();
  }

  const int Ro = by * BM, Co = bx * BM;
  const int col = lane & 15, rq = (lane >> 4) * 4;
#pragma unroll
  for (int m = 0; m < 4; ++m)
#pragma unroll
    for (int n2 = 0; n2 < 4; ++n2) {
      const int gr = Ro + wr * 64 + m * 16 + rq;
      const int gc = Co + wc * 64 + n2 * 16 + col;
#pragma unroll
      for (int j = 0; j < 4; ++j)
        out[(size_t)(gr + j) * N_CTX + gc] = acc[m][n2][j];
      if (bx != by) {
        *reinterpret_cast<float4*>(out + (size_t)gc * N_CTX + gr) =
            make_float4(acc[m][n2][0], acc[m][n2][1], acc[m][n2][2], acc[m][n2][3]);
      }
    }
}

// ---------------------------------------------------------------------------
// Kernel 2 (fallback): on-the-fly split + 3-product MFMA (ws too small path).
// ---------------------------------------------------------------------------
__device__ __forceinline__ void stage_half(char* __restrict__ hi_base,
                                           char* __restrict__ lo_base,
                                           const float4* cv, const float4* wv,
                                           float s, int r, int h) {
  unsigned hu[16], lu[16];
#pragma unroll
  for (int i = 0; i < 8; ++i) {
    float f[4] = {cv[i].x * wv[i].x * s, cv[i].y * wv[i].y * s,
                  cv[i].z * wv[i].z * s, cv[i].w * wv[i].w * s};
    unsigned hb[4], lb[4];
#pragma unroll
    for (int j = 0; j < 4; ++j) {
      hb[j] = f2bf(f[j]);
      float hf = __uint_as_float(hb[j] << 16);
      lb[j] = f2bf(f[j] - hf);
    }
    hu[2 * i] = hb[0] | (hb[1] << 16);
    hu[2 * i + 1] = hb[2] | (hb[3] << 16);
    lu[2 * i] = lb[0] | (lb[1] << 16);
    lu[2 * i + 1] = lb[2] | (lb[3] << 16);
  }
#pragma unroll
  for (int c = 0; c < 4; ++c) {
    int boff = r * 128 + SWZ(r, h * 64 + c * 16);
    *reinterpret_cast<uint4*>(hi_base + boff) =
        make_uint4(hu[4 * c], hu[4 * c + 1], hu[4 * c + 2], hu[4 * c + 3]);
    *reinterpret_cast<uint4*>(lo_base + boff) =
        make_uint4(lu[4 * c], lu[4 * c + 1], lu[4 * c + 2], lu[4 * c + 3]);
  }
}

__global__ __launch_bounds__(256, 2) void att_gemm(
    const float* __restrict__ ctx, const float* __restrict__ w,
    const float* __restrict__ invr, float* __restrict__ out) {
  const int bx = blockIdx.x, by = blockIdx.y;
  if (by > bx) return;

  __shared__ __align__(16) char Ahi[BM * 128];
  __shared__ __align__(16) char Alo[BM * 128];
  __shared__ __align__(16) char Bhi[BM * 128];
  __shared__ __align__(16) char Blo[BM * 128];

  const int t = threadIdx.x;
  const int lane = t & 63, wid = t >> 6;
  const int wr = wid >> 1, wc = wid & 1;
  const int Ro = by * BM, Co = bx * BM;
  const int srow = t >> 1;
  const int sh = t & 1;

  f32x4 acc[4][4] = {};

  for (int k0 = 0; k0 < KTOT; k0 += BK) {
    const int p = k0 >> 9;
    const int d0 = (k0 & (DIM - 1)) + sh * 32;

    float4 cva[8], cvb[8], wv[8];
    const float* wrow = w + (size_t)p * DIM + d0;
    const float* arow = ctx + (size_t)(Ro + srow) * DIM + d0;
    const float* brow = ctx + (size_t)(Co + srow) * DIM + d0;
#pragma unroll
    for (int i = 0; i < 8; ++i) {
      wv[i] = *reinterpret_cast<const float4*>(wrow + 4 * i);
      cva[i] = *reinterpret_cast<const float4*>(arow + 4 * i);
      cvb[i] = *reinterpret_cast<const float4*>(brow + 4 * i);
    }
    const float sA = invr[(size_t)p * N_CTX + Ro + srow];
    const float sB = invr[(size_t)p * N_CTX + Co + srow];

    __syncthreads();
    stage_half(Ahi, Alo, cva, wv, sA, srow, sh);
    stage_half(Bhi, Blo, cvb, wv, sB, srow, sh);
    __syncthreads();

#pragma unroll
    for (int ks = 0; ks < 2; ++ks) {
      const int kb = ks * 64 + (lane >> 4) * 16;
      bfrag ah[4], al[4], bh[4], bl[4];
#pragma unroll
      for (int m = 0; m < 4; ++m) {
        const int r = wr * 64 + m * 16 + (lane & 15);
        const int off = r * 128 + SWZ(r, kb);
        ah[m] = *reinterpret_cast<const bfrag*>(Ahi + off);
        al[m] = *reinterpret_cast<const bfrag*>(Alo + off);
      }
#pragma unroll
      for (int n = 0; n < 4; ++n) {
        const int r = wc * 64 + n * 16 + (lane & 15);
        const int off = r * 128 + SWZ(r, kb);
        bh[n] = *reinterpret_cast<const bfrag*>(Bhi + off);
        bl[n] = *reinterpret_cast<const bfrag*>(Blo + off);
      }
#pragma unroll
      for (int m = 0; m < 4; ++m)
#pragma unroll
        for (int n = 0; n < 4; ++n) {
          acc[m][n] = __builtin_amdgcn_mfma_f32_16x16x32_bf16(ah[m], bh[n], acc[m][n], 0, 0, 0);
          acc[m][n] = __builtin_amdgcn_mfma_f32_16x16x32_bf16(ah[m], bl[n], acc[m][n], 0, 0, 0);
          acc[m][n] = __builtin_amdgcn_mfma_f32_16x16x32_bf16(al[m], bh[n], acc[m][n], 0, 0, 0);
        }
    }
  }

  const int col = lane & 15, rq = (lane >> 4) * 4;
#pragma unroll
  for (int m = 0; m < 4; ++m)
#pragma unroll
    for (int n = 0; n < 4; ++n) {
      const int gr = Ro + wr * 64 + m * 16 + rq;
      const int gc = Co + wc * 64 + n * 16 + col;
#pragma unroll
      for (int j = 0; j < 4; ++j)
        out[(size_t)(gr + j) * N_CTX + gc] = acc[m][n][j];
      if (bx != by) {
        *reinterpret_cast<float4*>(out + (size_t)gc * N_CTX + gr) =
            make_float4(acc[m][n][0], acc[m][n][1], acc[m][n][2], acc[m][n][3]);
      }
    }
}

// ---------------------------------------------------------------------------
// Kernel 3: scan — UNCHANGED from R17-R22 (stores candV + nearEps flag).
// ---------------------------------------------------------------------------
__global__ __launch_bounds__(256) void topk_scan(
    float* __restrict__ att, int* __restrict__ candM,
    float* __restrict__ candV, int* __restrict__ cnt_g) {
  __shared__ unsigned red[2][4];
  __shared__ int lcnt, lg;

  const int n = blockIdx.x;
  const int t = threadIdx.x;
  const int wid = t >> 6, lane = t & 63;
  float* row = att + (size_t)n * N_CTX;

  float ar[16], tr[16];
  unsigned ur[16];
#pragma unroll
  for (int i = 0; i < 4; ++i) {
    float4 v4 = *reinterpret_cast<const float4*>(row + (size_t)(i * 256 + t) * 4);
    float tmp[4] = {v4.x, v4.y, v4.z, v4.w};
#pragma unroll
    for (int j = 0; j < 4; ++j) {
      float a = tmp[j];
      float tt = (a > EPS_NN) ? a : 0.0f;
      ar[i * 4 + j] = a;
      tr[i * 4 + j] = tt;
      ur[i * 4 + j] = __float_as_uint(tt);
    }
  }
  if (t == 0) { lcnt = 0; lg = 0; }

  unsigned lo = 0u, hi = 0x7F800000u;
  int buf = 0;
  while (lo < hi) {
    unsigned mid = lo + ((hi - lo) >> 1);
    unsigned c = 0;
#pragma unroll
    for (int i = 0; i < 16; ++i) c += (ur[i] > mid) ? 1u : 0u;
#pragma unroll
    for (int off = 32; off; off >>= 1) c += __shfl_down(c, off, 64);
    if (lane == 0) red[buf][wid] = c;
    __syncthreads();
    unsigned tot = red[buf][0] + red[buf][1] + red[buf][2] + red[buf][3];
    if (tot < TOPK_K) hi = mid; else lo = mid + 1;
    buf ^= 1;
  }
  const float vk = __uint_as_float(lo);
  const bool nearEps = (vk <= EPS_NN + 2.0f * DELTA);
  __syncthreads();   // lcnt/lg init visible

  unsigned myg = 0;
#pragma unroll
  for (int i = 0; i < 16; ++i) {
    const int blk = i >> 2, j = i & 3;
    const int m = (blk * 256 + t) * 4 + j;
    const float a = ar[i], tt = tr[i];
    const bool isEps = fabsf(a - EPS_NN) <= DELTA;
    const bool isOrd = (tt > 0.f) && (fabsf(tt - vk) <= DELTA);
    const bool cand = isOrd || (isEps && nearEps);
    const bool defIn = (tt > vk + DELTA) && !cand;
    tr[i] = defIn ? tt : 0.f;
    myg += defIn ? 1u : 0u;
    unsigned long long mask = __ballot(cand);
    if (mask) {
      int base = 0;
      if (lane == 0) base = atomicAdd(&lcnt, (int)__popcll(mask));
      base = __shfl(base, 0, 64);
      if (cand) {
        int pos = base + (int)__popcll(mask & ((1ull << lane) - 1ull));
        if (pos < CAP) {
          candM[n * CAP + pos] = m;
          candV[n * CAP + pos] = tt;
        }
      }
    }
  }
#pragma unroll
  for (int off = 32; off; off >>= 1) myg += __shfl_down(myg, off, 64);
  if (lane == 0) atomicAdd(&lg, (int)myg);

#pragma unroll
  for (int i = 0; i < 4; ++i) {
    *reinterpret_cast<float4*>(row + (size_t)(i * 256 + t) * 4) =
        make_float4(tr[i * 4], tr[i * 4 + 1], tr[i * 4 + 2], tr[i * 4 + 3]);
  }
  __syncthreads();
  if (t == 0) {
    cnt_g[4 * n] = (lcnt < CAP) ? lcnt : CAP;
    cnt_g[4 * n + 1] = lg;
    cnt_g[4 * n + 2] = nearEps ? 1 : 0;
  }
}

// ---------------------------------------------------------------------------
// Kernel 4: triage. R23: phases (a) skip and (b) refined (verbatim R22);
// ambiguous rows are APPENDED to a worklist and handled by repair_chain.
// ---------------------------------------------------------------------------
__global__ __launch_bounds__(64) void repair_select(
    const float* __restrict__ ctx, const float* __restrict__ w,
    const float* __restrict__ invr, const int* __restrict__ candM,
    const float* __restrict__ candV, const int* __restrict__ cnt_g,
    int* __restrict__ glist, int* __restrict__ gcount,
    float* __restrict__ att) {
  const int n = blockIdx.x;
  const int c = cnt_g[4 * n];
  if (c == 0) return;
  const int slots = TOPK_K - cnt_g[4 * n + 1];
  const int nearEps = cnt_g[4 * n + 2];
  const int j = threadIdx.x;

  if (c <= slots && !nearEps) {   // all candidates selected; approx values OK
    if (j < c) att[(size_t)n * N_CTX + candM[n * CAP + j]] = candV[n * CAP + j];
    return;
  }

  __shared__ int m_s[CAP];
  __shared__ float rv_s[CAP];    // refined, post-eps
  __shared__ float rr_s[CAP];    // refined, raw
  if (j < c) m_s[j] = candM[n * CAP + j];
  __syncthreads();

  // ---- Phase (b): refined values, wave-parallel, 8 independent accums ----
  const float* cn = ctx + (size_t)n * DIM;
  for (int q = 0; q < c; ++q) {
    const int mq = m_s[q];
    const float* cm = ctx + (size_t)mq * DIM;
    float acc8[8] = {0.f, 0.f, 0.f, 0.f, 0.f, 0.f, 0.f, 0.f};
    for (int p = 0; p < NPERS; ++p) {
      const float sA = invr[(size_t)p * N_CTX + n];
      const float sB = invr[(size_t)p * N_CTX + mq];
      const float* wp = w + (size_t)p * DIM;
#pragma unroll
      for (int i2 = 0; i2 < 8; ++i2) {
        const int d = j + 64 * i2;      // coalesced: 64 consecutive floats
        const float fa = (cn[d] * wp[d]) * sA;
        const float fb = (cm[d] * wp[d]) * sB;
        acc8[i2] = fmaf(fa, fb, acc8[i2]);
      }
    }
    float part = ((acc8[0] + acc8[1]) + (acc8[2] + acc8[3])) +
                 ((acc8[4] + acc8[5]) + (acc8[6] + acc8[7]));
#pragma unroll
    for (int off = 32; off; off >>= 1) part += __shfl_down(part, off, 64);
    if (j == 0) {
      rr_s[q] = part;
      rv_s[q] = (part > EPS_NN) ? part : 0.f;
    }
  }
  __syncthreads();

  // rank refined; ambiguity test
  bool kept = false;
  float rv = 0.f, rr = 0.f;
  if (j < c) {
    rv = rv_s[j];
    rr = rr_s[j];
    const int m = m_s[j];
    int rank = 0;
    for (int i = 0; i < c; ++i) {
      if (i == j) continue;
      rank += ((rv_s[i] > rv) || (rv_s[i] == rv && m_s[i] < m)) ? 1 : 0;
    }
    kept = (rank < slots);
  }
  float mk = (j < c && kept) ? rv : 3.4e38f;        // min kept value
  float mo = (j < c && !kept) ? rv : -3.4e38f;      // max out value
  float ea = (j < c && fabsf(rr - EPS_NN) <= DELTA2) ? 1.f : 0.f;
#pragma unroll
  for (int off = 32; off; off >>= 1) {
    mk = fminf(mk, __shfl_down(mk, off, 64));
    mo = fmaxf(mo, __shfl_down(mo, off, 64));
    ea = fmaxf(ea, __shfl_down(ea, off, 64));
  }
  mk = __shfl(mk, 0, 64);
  mo = __shfl(mo, 0, 64);
  ea = __shfl(ea, 0, 64);
  const bool ambiguous = (mk - mo <= DELTA2) || (ea > 0.f);

  if (ambiguous) {
    if (j == 0) {                 // defer to repair_chain
      int gp = atomicAdd(gcount, 1);
      glist[gp] = n;
    }
    return;
  }
  if (j < c && kept) att[(size_t)n * N_CTX + m_s[j]] = rv;
}

// ---------------------------------------------------------------------------
// Kernel 5: exact chain for ambiguous rows only (worklist). LDS-resident
// operands: w (32KB), cn (2KB), first CAPL candidate rows (stride 516 ->
// active-lane reads <=2-way banked). Chain is VERBATIM the locked R2 chain
// (same values — LDS holds exact copies — same fmaf order -> bit-identical).
// ---------------------------------------------------------------------------
__global__ __launch_bounds__(64) void repair_chain(
    const float* __restrict__ ctx, const float* __restrict__ w,
    const float* __restrict__ invr, const int* __restrict__ candM,
    const int* __restrict__ cnt_g, const int* __restrict__ glist,
    const int* __restrict__ gcount, float* __restrict__ att) {
  if (blockIdx.x >= gcount[0]) return;
  const int n = glist[blockIdx.x];
  const int c = cnt_g[4 * n];
  const int slots = TOPK_K - cnt_g[4 * n + 1];
  const int j = threadIdx.x;

  __shared__ __align__(16) float wL[KTOT];        // 32 KB
  __shared__ __align__(16) float cnL[DIM];        // 2 KB
  __shared__ __align__(16) float cmL[CAPL][516];  // ~24.2 KB
  __shared__ float te_s[CAP];
  __shared__ int m_s[CAP];

  if (j < c) m_s[j] = candM[n * CAP + j];
  __syncthreads();

  // cooperative staging (coalesced float4)
  {
    const float4* wg = reinterpret_cast<const float4*>(w);
    float4* wl = reinterpret_cast<float4*>(wL);
#pragma unroll
    for (int i = 0; i < 32; ++i) wl[i * 64 + j] = wg[i * 64 + j];
    const float4* cg = reinterpret_cast<const float4*>(ctx + (size_t)n * DIM);
    float4* cl = reinterpret_cast<float4*>(cnL);
#pragma unroll
    for (int i = 0; i < 2; ++i) cl[i * 64 + j] = cg[i * 64 + j];
    const int cl2 = (c < CAPL) ? c : CAPL;
    for (int r = 0; r < cl2; ++r) {
      const float4* mg = reinterpret_cast<const float4*>(ctx + (size_t)m_s[r] * DIM);
      float4* ml = reinterpret_cast<float4*>(&cmL[r][0]);
#pragma unroll
      for (int i = 0; i < 2; ++i) ml[i * 64 + j] = mg[i * 64 + j];
    }
  }
  __syncthreads();

  float te = -1.f;
  int m = -1;
  if (j < c) {
    m = m_s[j];
    const float4* cn4 = reinterpret_cast<const float4*>(cnL);
    const float4* cm4 = (j < CAPL)
        ? reinterpret_cast<const float4*>(&cmL[j][0])
        : reinterpret_cast<const float4*>(ctx + (size_t)m * DIM);
    float e = 0.f;
    for (int p = 0; p < NPERS; ++p) {
      const float sA = invr[(size_t)p * N_CTX + n];
      const float sB = invr[(size_t)p * N_CTX + m];
      const float4* w4 = reinterpret_cast<const float4*>(wL + p * DIM);
#pragma unroll 4
      for (int q = 0; q < DIM / 4; ++q) {
        const float4 a = cn4[q], b = cm4[q], ww = w4[q];
        e = fmaf((a.x * ww.x) * sA, (b.x * ww.x) * sB, e);
        e = fmaf((a.y * ww.y) * sA, (b.y * ww.y) * sB, e);
        e = fmaf((a.z * ww.z) * sA, (b.z * ww.z) * sB, e);
        e = fmaf((a.w * ww.w) * sA, (b.w * ww.w) * sB, e);
      }
    }
    te = (e > EPS_NN) ? e : 0.f;
  }
  te_s[j] = te;
  __syncthreads();
  if (j < c) {
    int rank = 0;
    for (int i = 0; i < c; ++i) {
      if (i == j) continue;
      rank += ((te_s[i] > te) || (te_s[i] == te && m_s[i] < m)) ? 1 : 0;
    }
    if (rank < slots) att[(size_t)n * N_CTX + m] = te;
  }
}

// ---------------------------------------------------------------------------
extern "C" void kernel_launch(void* const* d_in, const int* in_sizes, int n_in,
                              void* d_out, int out_size, void* d_ws, size_t ws_size,
                              hipStream_t stream) {
  const float* ctx = (const float*)d_in[0];   // (4096, 512)
  const float* w   = (const float*)d_in[1];   // (16, 512)
  float* out = (float*)d_out;                 // (4096, 4096)

  // ws: invr 256K | cnt_g 64K | candM 1M | candV 1M | glist 16K | gcount 4K | Fhi 64M
  const size_t OFF_CNT = 262144;
  const size_t OFF_CAND = OFF_CNT + 65536;
  const size_t OFF_CV = OFF_CAND + 1048576;
  const size_t OFF_GL = OFF_CV + 1048576;
  const size_t OFF_GC = OFF_GL + 16384;
  const size_t OFF_FHI = OFF_GC + 4096;
  const size_t FSZ = (size_t)32 * NKSTEP * CHUNK;       // 67108864
  float* invr = (float*)d_ws;
  int* cnt_g = (int*)((char*)d_ws + OFF_CNT);
  int* candM = (int*)((char*)d_ws + OFF_CAND);
  float* candV = (float*)((char*)d_ws + OFF_CV);
  int* glist = (int*)((char*)d_ws + OFF_GL);
  int* gcount = (int*)((char*)d_ws + OFF_GC);
  unsigned short* Fhi = (unsigned short*)((char*)d_ws + OFF_FHI);
  const bool haveF = ws_size >= OFF_FHI + FSZ;

  if (haveF) {
    split_norms_kernel<<<(N_CTX * 64) / 256, 256, 0, stream>>>(ctx, w, invr, Fhi, gcount);
    att_gemm_fast<<<528, 256, 0, stream>>>(Fhi, out);
  } else {
    norms_kernel<<<(NPERS * N_CTX) / 4, 256, 0, stream>>>(ctx, w, invr, gcount);
    dim3 grid(N_CTX / BM, N_CTX / BM);
    att_gemm<<<grid, 256, 0, stream>>>(ctx, w, invr, out);
  }

  topk_scan<<<N_CTX, 256, 0, stream>>>(out, candM, candV, cnt_g);
  repair_select<<<N_CTX, 64, 0, stream>>>(ctx, w, invr, candM, candV, cnt_g,
                                          glist, gcount, out);
  repair_chain<<<N_CTX, 64, 0, stream>>>(ctx, w, invr, candM, cnt_g,
                                         glist, gcount, out);
}

// Round 24
// 399.905 us; speedup vs baseline: 1.6848x; 1.0242x over previous
//
#include <hip/hip_runtime.h>
#include <math.h>
#include <stdint.h>

#define N_CTX 4096
#define DIM 512
#define NPERS 16
#define KTOT (NPERS * DIM)   // 8192
#define EPS_NN 0.1f
#define TOPK_K 30

#define DELTA 4e-4f          // GEMM-vs-chain margin (validated R18+)
#define DELTA2 1e-5f         // refined-vs-chain margin (order noise ~4e-7 RMS)
#define CAP 64               // max candidates per row
#define CAPL 12              // cm rows staged in LDS inside repair_chain
#define RCAP 256             // compact list capacity per row (~47 expected)

#define BM 128
#define BK 64
#define NKSTEP (KTOT / BK)   // 128
#define CHUNK 16384

typedef __attribute__((ext_vector_type(8))) short bfrag;
typedef __attribute__((ext_vector_type(4))) float f32x4;

__device__ __forceinline__ unsigned short f2bf(float f) {
  unsigned u = __float_as_uint(f);
  unsigned r = u + 0x7FFFu + ((u >> 16) & 1u);
  return (unsigned short)(r >> 16);
}

#define SWZ(r, b) ((b) ^ (((r) & 7) << 4))

__device__ __forceinline__ void stage1k(const char* gsrc, char* ldst, int lane) {
#if __has_builtin(__builtin_amdgcn_global_load_lds)
  __builtin_amdgcn_global_load_lds(
      (const __attribute__((address_space(1))) unsigned int*)(uintptr_t)(gsrc + lane * 16),
      (__attribute__((address_space(3))) unsigned int*)(uintptr_t)ldst, 16, 0, 0);
#else
  *reinterpret_cast<uint4*>(ldst + lane * 16) =
      *reinterpret_cast<const uint4*>(gsrc + lane * 16);
#endif
}

// ---------------------------------------------------------------------------
// Kernel 1 (fallback only)
// ---------------------------------------------------------------------------
__global__ __launch_bounds__(256) void norms_kernel(
    const float* __restrict__ ctx, const float* __restrict__ w,
    float* __restrict__ invr, int* __restrict__ gcount) {
  int wid = threadIdx.x >> 6;
  int lane = threadIdx.x & 63;
  int gid = blockIdx.x * 4 + wid;
  if (blockIdx.x == 0 && threadIdx.x == 0) gcount[0] = 0;
  int p = gid >> 12;
  int n = gid & (N_CTX - 1);
  const float4* c4 = reinterpret_cast<const float4*>(ctx + (size_t)n * DIM + lane * 8);
  const float4* w4 = reinterpret_cast<const float4*>(w + (size_t)p * DIM + lane * 8);
  float4 c0 = c4[0], c1 = c4[1];
  float4 w0 = w4[0], w1 = w4[1];
  float s = 0.f, v;
  v = c0.x * w0.x; s = fmaf(v, v, s);
  v = c0.y * w0.y; s = fmaf(v, v, s);
  v = c0.z * w0.z; s = fmaf(v, v, s);
  v = c0.w * w0.w; s = fmaf(v, v, s);
  v = c1.x * w1.x; s = fmaf(v, v, s);
  v = c1.y * w1.y; s = fmaf(v, v, s);
  v = c1.z * w1.z; s = fmaf(v, v, s);
  v = c1.w * w1.w; s = fmaf(v, v, s);
#pragma unroll
  for (int off = 32; off; off >>= 1) s += __shfl_down(s, off, 64);
  if (lane == 0) invr[(size_t)p * N_CTX + n] = 0.25f / fmaxf(sqrtf(s), 1e-12f);
}

// ---------------------------------------------------------------------------
// Kernel 1+1b FUSED: norms (bit-identical chain) + bf16-hi split.
// R24: also zeroes gcount and the per-row compact counters rcnt.
// ---------------------------------------------------------------------------
__global__ __launch_bounds__(256) void split_norms_kernel(
    const float* __restrict__ ctx, const float* __restrict__ w,
    float* __restrict__ invr, unsigned short* __restrict__ Fhi,
    int* __restrict__ gcount, int* __restrict__ rcnt) {
  const int tid = blockIdx.x * 256 + threadIdx.x;
  if (tid == 0) gcount[0] = 0;
  if (tid < N_CTX) rcnt[tid] = 0;
  const int n = tid >> 6;
  const int db = tid & 63;
  const int d0 = db * 8;
  const int P = n >> 7;
  const int r = n & 127;
  const int sl = db & 7;
  const int swzoff = r * 128 + ((sl * 16) ^ ((r & 7) << 4));

  const float4 c0 = *reinterpret_cast<const float4*>(ctx + (size_t)n * DIM + d0);
  const float4 c1 = *reinterpret_cast<const float4*>(ctx + (size_t)n * DIM + d0 + 4);

#pragma unroll
  for (int p = 0; p < NPERS; ++p) {
    const float4 w0 = *reinterpret_cast<const float4*>(w + (size_t)p * DIM + d0);
    const float4 w1 = *reinterpret_cast<const float4*>(w + (size_t)p * DIM + d0 + 4);

    float pr[8] = {c0.x * w0.x, c0.y * w0.y, c0.z * w0.z, c0.w * w0.w,
                   c1.x * w1.x, c1.y * w1.y, c1.z * w1.z, c1.w * w1.w};

    float s = 0.f;
#pragma unroll
    for (int j = 0; j < 8; ++j) s = fmaf(pr[j], pr[j], s);
#pragma unroll
    for (int off = 32; off; off >>= 1) s += __shfl_down(s, off, 64);
    const float stot = __shfl(s, 0, 64);
    const float sc = 0.25f / fmaxf(sqrtf(stot), 1e-12f);
    if (db == 0) invr[(size_t)p * N_CTX + n] = sc;

    unsigned hb[8];
#pragma unroll
    for (int j = 0; j < 8; ++j) hb[j] = f2bf(pr[j] * sc);
    uint4 hv = make_uint4(hb[0] | (hb[1] << 16), hb[2] | (hb[3] << 16),
                          hb[4] | (hb[5] << 16), hb[6] | (hb[7] << 16));
    const int kstep = p * 8 + (db >> 3);
    const size_t base = (size_t)(P * 128 + kstep) * CHUNK + swzoff;
    *reinterpret_cast<uint4*>((char*)Fhi + base) = hv;
  }
}

// ---------------------------------------------------------------------------
// Kernel 2 (fast): single-product bf16 MFMA GEMM. R24: epilogue appends
// compact (col,val) pairs for entries > eps-DELTA instead of dense stores.
// Entries below eps-DELTA are provably outside the output (|err|<=2.44e-4).
// List order nondeterministic, but selection ranks by (value,index) ->
// output invariant.
// ---------------------------------------------------------------------------
__global__ __launch_bounds__(256, 3) void att_gemm_fast(
    const unsigned short* __restrict__ Fhi, int* __restrict__ rcnt,
    int* __restrict__ rlistM, float* __restrict__ rlistV) {
  const int bid0 = blockIdx.x;
  int bid = (bid0 & 7) * 66 + (bid0 >> 3);
  int by = 0;
  while (bid >= (by + 1) * 32 - ((by + 1) * by) / 2) ++by;
  const int bx = by + (bid - (by * 32 - (by * (by - 1)) / 2));

  __shared__ __align__(16) char Ahi[CHUNK];
  __shared__ __align__(16) char Bhi[CHUNK];

  const int t = threadIdx.x;
  const int lane = t & 63, wid = t >> 6;
  const int wr = wid >> 1, wc = wid & 1;
  const int woff = __builtin_amdgcn_readfirstlane(wid * 4096);

  const char* gAh = (const char*)Fhi + (size_t)by * NKSTEP * CHUNK + woff;
  const char* gBh = (const char*)Fhi + (size_t)bx * NKSTEP * CHUNK + woff;

  f32x4 acc[4][4] = {};

  for (int s = 0; s < NKSTEP; ++s) {
    const size_t so = (size_t)s * CHUNK;
#pragma unroll
    for (int i = 0; i < 4; ++i) {
      stage1k(gAh + so + i * 1024, Ahi + woff + i * 1024, lane);
      stage1k(gBh + so + i * 1024, Bhi + woff + i * 1024, lane);
    }
    __syncthreads();

#pragma unroll
    for (int ks = 0; ks < 2; ++ks) {
      const int kb = ks * 64 + (lane >> 4) * 16;
      bfrag ah[4], bh[4];
#pragma unroll
      for (int m = 0; m < 4; ++m) {
        const int r = wr * 64 + m * 16 + (lane & 15);
        ah[m] = *reinterpret_cast<const bfrag*>(Ahi + r * 128 + SWZ(r, kb));
      }
#pragma unroll
      for (int n2 = 0; n2 < 4; ++n2) {
        const int r = wc * 64 + n2 * 16 + (lane & 15);
        bh[n2] = *reinterpret_cast<const bfrag*>(Bhi + r * 128 + SWZ(r, kb));
      }
#pragma unroll
      for (int m = 0; m < 4; ++m)
#pragma unroll
        for (int n2 = 0; n2 < 4; ++n2)
          acc[m][n2] = __builtin_amdgcn_mfma_f32_16x16x32_bf16(ah[m], bh[n2], acc[m][n2], 0, 0, 0);
    }
    __syncthreads();
  }

  const int Ro = by * BM, Co = bx * BM;
  const int col = lane & 15, rq = (lane >> 4) * 4;
  const float TH = EPS_NN - DELTA;
#pragma unroll
  for (int m = 0; m < 4; ++m)
#pragma unroll
    for (int n2 = 0; n2 < 4; ++n2) {
      const int gr = Ro + wr * 64 + m * 16 + rq;
      const int gc = Co + wc * 64 + n2 * 16 + col;
#pragma unroll
      for (int j = 0; j < 4; ++j) {
        const float v = acc[m][n2][j];
        if (v > TH) {
          int pos = atomicAdd(&rcnt[gr + j], 1);
          if (pos < RCAP) {
            rlistM[(size_t)(gr + j) * RCAP + pos] = gc;
            rlistV[(size_t)(gr + j) * RCAP + pos] = v;
          }
          if (bx != by) {       // mirrored entry: row gc, col gr+j
            int pos2 = atomicAdd(&rcnt[gc], 1);
            if (pos2 < RCAP) {
              rlistM[(size_t)gc * RCAP + pos2] = gr + j;
              rlistV[(size_t)gc * RCAP + pos2] = v;
            }
          }
        }
      }
    }
}

// ---------------------------------------------------------------------------
// Kernel 2 (fallback): on-the-fly split + 3-product MFMA, dense stores.
// ---------------------------------------------------------------------------
__device__ __forceinline__ void stage_half(char* __restrict__ hi_base,
                                           char* __restrict__ lo_base,
                                           const float4* cv, const float4* wv,
                                           float s, int r, int h) {
  unsigned hu[16], lu[16];
#pragma unroll
  for (int i = 0; i < 8; ++i) {
    float f[4] = {cv[i].x * wv[i].x * s, cv[i].y * wv[i].y * s,
                  cv[i].z * wv[i].z * s, cv[i].w * wv[i].w * s};
    unsigned hb[4], lb[4];
#pragma unroll
    for (int j = 0; j < 4; ++j) {
      hb[j] = f2bf(f[j]);
      float hf = __uint_as_float(hb[j] << 16);
      lb[j] = f2bf(f[j] - hf);
    }
    hu[2 * i] = hb[0] | (hb[1] << 16);
    hu[2 * i + 1] = hb[2] | (hb[3] << 16);
    lu[2 * i] = lb[0] | (lb[1] << 16);
    lu[2 * i + 1] = lb[2] | (lb[3] << 16);
  }
#pragma unroll
  for (int c = 0; c < 4; ++c) {
    int boff = r * 128 + SWZ(r, h * 64 + c * 16);
    *reinterpret_cast<uint4*>(hi_base + boff) =
        make_uint4(hu[4 * c], hu[4 * c + 1], hu[4 * c + 2], hu[4 * c + 3]);
    *reinterpret_cast<uint4*>(lo_base + boff) =
        make_uint4(lu[4 * c], lu[4 * c + 1], lu[4 * c + 2], lu[4 * c + 3]);
  }
}

__global__ __launch_bounds__(256, 2) void att_gemm(
    const float* __restrict__ ctx, const float* __restrict__ w,
    const float* __restrict__ invr, float* __restrict__ out) {
  const int bx = blockIdx.x, by = blockIdx.y;
  if (by > bx) return;

  __shared__ __align__(16) char Ahi[BM * 128];
  __shared__ __align__(16) char Alo[BM * 128];
  __shared__ __align__(16) char Bhi[BM * 128];
  __shared__ __align__(16) char Blo[BM * 128];

  const int t = threadIdx.x;
  const int lane = t & 63, wid = t >> 6;
  const int wr = wid >> 1, wc = wid & 1;
  const int Ro = by * BM, Co = bx * BM;
  const int srow = t >> 1;
  const int sh = t & 1;

  f32x4 acc[4][4] = {};

  for (int k0 = 0; k0 < KTOT; k0 += BK) {
    const int p = k0 >> 9;
    const int d0 = (k0 & (DIM - 1)) + sh * 32;

    float4 cva[8], cvb[8], wv[8];
    const float* wrow = w + (size_t)p * DIM + d0;
    const float* arow = ctx + (size_t)(Ro + srow) * DIM + d0;
    const float* brow = ctx + (size_t)(Co + srow) * DIM + d0;
#pragma unroll
    for (int i = 0; i < 8; ++i) {
      wv[i] = *reinterpret_cast<const float4*>(wrow + 4 * i);
      cva[i] = *reinterpret_cast<const float4*>(arow + 4 * i);
      cvb[i] = *reinterpret_cast<const float4*>(brow + 4 * i);
    }
    const float sA = invr[(size_t)p * N_CTX + Ro + srow];
    const float sB = invr[(size_t)p * N_CTX + Co + srow];

    __syncthreads();
    stage_half(Ahi, Alo, cva, wv, sA, srow, sh);
    stage_half(Bhi, Blo, cvb, wv, sB, srow, sh);
    __syncthreads();

#pragma unroll
    for (int ks = 0; ks < 2; ++ks) {
      const int kb = ks * 64 + (lane >> 4) * 16;
      bfrag ah[4], al[4], bh[4], bl[4];
#pragma unroll
      for (int m = 0; m < 4; ++m) {
        const int r = wr * 64 + m * 16 + (lane & 15);
        const int off = r * 128 + SWZ(r, kb);
        ah[m] = *reinterpret_cast<const bfrag*>(Ahi + off);
        al[m] = *reinterpret_cast<const bfrag*>(Alo + off);
      }
#pragma unroll
      for (int n = 0; n < 4; ++n) {
        const int r = wc * 64 + n * 16 + (lane & 15);
        const int off = r * 128 + SWZ(r, kb);
        bh[n] = *reinterpret_cast<const bfrag*>(Bhi + off);
        bl[n] = *reinterpret_cast<const bfrag*>(Blo + off);
      }
#pragma unroll
      for (int m = 0; m < 4; ++m)
#pragma unroll
        for (int n = 0; n < 4; ++n) {
          acc[m][n] = __builtin_amdgcn_mfma_f32_16x16x32_bf16(ah[m], bh[n], acc[m][n], 0, 0, 0);
          acc[m][n] = __builtin_amdgcn_mfma_f32_16x16x32_bf16(ah[m], bl[n], acc[m][n], 0, 0, 0);
          acc[m][n] = __builtin_amdgcn_mfma_f32_16x16x32_bf16(al[m], bh[n], acc[m][n], 0, 0, 0);
        }
    }
  }

  const int col = lane & 15, rq = (lane >> 4) * 4;
#pragma unroll
  for (int m = 0; m < 4; ++m)
#pragma unroll
    for (int n = 0; n < 4; ++n) {
      const int gr = Ro + wr * 64 + m * 16 + rq;
      const int gc = Co + wc * 64 + n * 16 + col;
#pragma unroll
      for (int j = 0; j < 4; ++j)
        out[(size_t)(gr + j) * N_CTX + gc] = acc[m][n][j];
      if (bx != by) {
        *reinterpret_cast<float4*>(out + (size_t)gc * N_CTX + gr) =
            make_float4(acc[m][n][0], acc[m][n][1], acc[m][n][2], acc[m][n][3]);
      }
    }
}

// ---------------------------------------------------------------------------
// Kernel 3 (fallback): dense scan (R23 verbatim).
// ---------------------------------------------------------------------------
__global__ __launch_bounds__(256) void topk_scan(
    float* __restrict__ att, int* __restrict__ candM,
    float* __restrict__ candV, int* __restrict__ cnt_g) {
  __shared__ unsigned red[2][4];
  __shared__ int lcnt, lg;

  const int n = blockIdx.x;
  const int t = threadIdx.x;
  const int wid = t >> 6, lane = t & 63;
  float* row = att + (size_t)n * N_CTX;

  float ar[16], tr[16];
  unsigned ur[16];
#pragma unroll
  for (int i = 0; i < 4; ++i) {
    float4 v4 = *reinterpret_cast<const float4*>(row + (size_t)(i * 256 + t) * 4);
    float tmp[4] = {v4.x, v4.y, v4.z, v4.w};
#pragma unroll
    for (int j = 0; j < 4; ++j) {
      float a = tmp[j];
      float tt = (a > EPS_NN) ? a : 0.0f;
      ar[i * 4 + j] = a;
      tr[i * 4 + j] = tt;
      ur[i * 4 + j] = __float_as_uint(tt);
    }
  }
  if (t == 0) { lcnt = 0; lg = 0; }

  unsigned lo = 0u, hi = 0x7F800000u;
  int buf = 0;
  while (lo < hi) {
    unsigned mid = lo + ((hi - lo) >> 1);
    unsigned c = 0;
#pragma unroll
    for (int i = 0; i < 16; ++i) c += (ur[i] > mid) ? 1u : 0u;
#pragma unroll
    for (int off = 32; off; off >>= 1) c += __shfl_down(c, off, 64);
    if (lane == 0) red[buf][wid] = c;
    __syncthreads();
    unsigned tot = red[buf][0] + red[buf][1] + red[buf][2] + red[buf][3];
    if (tot < TOPK_K) hi = mid; else lo = mid + 1;
    buf ^= 1;
  }
  const float vk = __uint_as_float(lo);
  const bool nearEps = (vk <= EPS_NN + 2.0f * DELTA);
  __syncthreads();

  unsigned myg = 0;
#pragma unroll
  for (int i = 0; i < 16; ++i) {
    const int blk = i >> 2, j = i & 3;
    const int m = (blk * 256 + t) * 4 + j;
    const float a = ar[i], tt = tr[i];
    const bool isEps = fabsf(a - EPS_NN) <= DELTA;
    const bool isOrd = (tt > 0.f) && (fabsf(tt - vk) <= DELTA);
    const bool cand = isOrd || (isEps && nearEps);
    const bool defIn = (tt > vk + DELTA) && !cand;
    tr[i] = defIn ? tt : 0.f;
    myg += defIn ? 1u : 0u;
    unsigned long long mask = __ballot(cand);
    if (mask) {
      int base = 0;
      if (lane == 0) base = atomicAdd(&lcnt, (int)__popcll(mask));
      base = __shfl(base, 0, 64);
      if (cand) {
        int pos = base + (int)__popcll(mask & ((1ull << lane) - 1ull));
        if (pos < CAP) {
          candM[n * CAP + pos] = m;
          candV[n * CAP + pos] = tt;
        }
      }
    }
  }
#pragma unroll
  for (int off = 32; off; off >>= 1) myg += __shfl_down(myg, off, 64);
  if (lane == 0) atomicAdd(&lg, (int)myg);

#pragma unroll
  for (int i = 0; i < 4; ++i) {
    *reinterpret_cast<float4*>(row + (size_t)(i * 256 + t) * 4) =
        make_float4(tr[i * 4], tr[i * 4 + 1], tr[i * 4 + 2], tr[i * 4 + 3]);
  }
  __syncthreads();
  if (t == 0) {
    cnt_g[4 * n] = (lcnt < CAP) ? lcnt : CAP;
    cnt_g[4 * n + 1] = lg;
    cnt_g[4 * n + 2] = nearEps ? 1 : 0;
  }
}

// ---------------------------------------------------------------------------
// Kernel 4 (fallback): R23 triage verbatim (skip + refined + defer).
// ---------------------------------------------------------------------------
__global__ __launch_bounds__(64) void repair_select(
    const float* __restrict__ ctx, const float* __restrict__ w,
    const float* __restrict__ invr, const int* __restrict__ candM,
    const float* __restrict__ candV, const int* __restrict__ cnt_g,
    int* __restrict__ glist, int* __restrict__ gcount,
    float* __restrict__ att) {
  const int n = blockIdx.x;
  const int c = cnt_g[4 * n];
  if (c == 0) return;
  const int slots = TOPK_K - cnt_g[4 * n + 1];
  const int nearEps = cnt_g[4 * n + 2];
  const int j = threadIdx.x;

  if (c <= slots && !nearEps) {
    if (j < c) att[(size_t)n * N_CTX + candM[n * CAP + j]] = candV[n * CAP + j];
    return;
  }

  __shared__ int m_s[CAP];
  __shared__ float rv_s[CAP];
  __shared__ float rr_s[CAP];
  if (j < c) m_s[j] = candM[n * CAP + j];
  __syncthreads();

  const float* cn = ctx + (size_t)n * DIM;
  for (int q = 0; q < c; ++q) {
    const int mq = m_s[q];
    const float* cm = ctx + (size_t)mq * DIM;
    float acc8[8] = {0.f, 0.f, 0.f, 0.f, 0.f, 0.f, 0.f, 0.f};
    for (int p = 0; p < NPERS; ++p) {
      const float sA = invr[(size_t)p * N_CTX + n];
      const float sB = invr[(size_t)p * N_CTX + mq];
      const float* wp = w + (size_t)p * DIM;
#pragma unroll
      for (int i2 = 0; i2 < 8; ++i2) {
        const int d = j + 64 * i2;
        const float fa = (cn[d] * wp[d]) * sA;
        const float fb = (cm[d] * wp[d]) * sB;
        acc8[i2] = fmaf(fa, fb, acc8[i2]);
      }
    }
    float part = ((acc8[0] + acc8[1]) + (acc8[2] + acc8[3])) +
                 ((acc8[4] + acc8[5]) + (acc8[6] + acc8[7]));
#pragma unroll
    for (int off = 32; off; off >>= 1) part += __shfl_down(part, off, 64);
    if (j == 0) {
      rr_s[q] = part;
      rv_s[q] = (part > EPS_NN) ? part : 0.f;
    }
  }
  __syncthreads();

  bool kept = false;
  float rv = 0.f, rr = 0.f;
  if (j < c) {
    rv = rv_s[j];
    rr = rr_s[j];
    const int m = m_s[j];
    int rank = 0;
    for (int i = 0; i < c; ++i) {
      if (i == j) continue;
      rank += ((rv_s[i] > rv) || (rv_s[i] == rv && m_s[i] < m)) ? 1 : 0;
    }
    kept = (rank < slots);
  }
  float mk = (j < c && kept) ? rv : 3.4e38f;
  float mo = (j < c && !kept) ? rv : -3.4e38f;
  float ea = (j < c && fabsf(rr - EPS_NN) <= DELTA2) ? 1.f : 0.f;
#pragma unroll
  for (int off = 32; off; off >>= 1) {
    mk = fminf(mk, __shfl_down(mk, off, 64));
    mo = fmaxf(mo, __shfl_down(mo, off, 64));
    ea = fmaxf(ea, __shfl_down(ea, off, 64));
  }
  mk = __shfl(mk, 0, 64);
  mo = __shfl(mo, 0, 64);
  ea = __shfl(ea, 0, 64);
  const bool ambiguous = (mk - mo <= DELTA2) || (ea > 0.f);

  if (ambiguous) {
    if (j == 0) {
      int gp = atomicAdd(gcount, 1);
      glist[gp] = n;
    }
    return;
  }
  if (j < c && kept) att[(size_t)n * N_CTX + m_s[j]] = rv;
}

// ---------------------------------------------------------------------------
// Kernel 4' (fast path): fused select on COMPACT lists. One 64-thread block
// per row. vk = min{tt_i > 0 : #(tt_j > tt_i) <= 29} (== binary-search vk);
// classification formulas VERBATIM; defIn -> direct sparse store (att is
// memset-zeroed); skip / refined-triage / defer logic verbatim from R23.
// ---------------------------------------------------------------------------
__global__ __launch_bounds__(64) void select_compact(
    const float* __restrict__ ctx, const float* __restrict__ w,
    const float* __restrict__ invr, const int* __restrict__ rcnt,
    const int* __restrict__ rlistM, const float* __restrict__ rlistV,
    int* __restrict__ candM, int* __restrict__ cnt_g,
    int* __restrict__ glist, int* __restrict__ gcount,
    float* __restrict__ att) {
  const int n = blockIdx.x;
  const int j = threadIdx.x;
  int nc = rcnt[n];
  if (nc > RCAP) nc = RCAP;
  if (nc == 0) return;

  __shared__ int mL[RCAP];
  __shared__ float vL[RCAP];
  __shared__ float ttL[RCAP];
  __shared__ int cM[CAP];
  __shared__ float cV[CAP];
  __shared__ int lc;
  if (j == 0) lc = 0;
  for (int i = j; i < nc; i += 64) {
    const float a = rlistV[(size_t)n * RCAP + i];
    mL[i] = rlistM[(size_t)n * RCAP + i];
    vL[i] = a;
    ttL[i] = (a > EPS_NN) ? a : 0.f;
  }
  __syncthreads();

  // per-entry strictly-greater counts; vk + positive count
  float vkLoc = 3.4e38f;
  int posLoc = 0;
  float ttOwn[4];
  int gtOwn[4];
#pragma unroll
  for (int s = 0; s < 4; ++s) { ttOwn[s] = -1.f; gtOwn[s] = 0; }
#pragma unroll
  for (int s = 0; s < 4; ++s) {
    const int idx = j + s * 64;
    if (idx < nc) {
      const float t = ttL[idx];
      ttOwn[s] = t;
      posLoc += (t > 0.f) ? 1 : 0;
      int g = 0;
      for (int i = 0; i < nc; ++i) g += (ttL[i] > t) ? 1 : 0;
      gtOwn[s] = g;
      if (t > 0.f && g <= TOPK_K - 1) vkLoc = fminf(vkLoc, t);
    }
  }
#pragma unroll
  for (int off = 32; off; off >>= 1) {
    posLoc += __shfl_down(posLoc, off, 64);
    vkLoc = fminf(vkLoc, __shfl_down(vkLoc, off, 64));
  }
  const int pos = __shfl(posLoc, 0, 64);
  float vk = __shfl(vkLoc, 0, 64);
  if (pos < TOPK_K) vk = 0.f;
  const bool nearEps = (vk <= EPS_NN + 2.0f * DELTA);

  // classify; write defIn; collect cands
  int gLoc = 0;
#pragma unroll
  for (int s = 0; s < 4; ++s) {
    const int idx = j + s * 64;
    if (idx < nc) {
      const float a = vL[idx], tt = ttOwn[s];
      const bool isEps = fabsf(a - EPS_NN) <= DELTA;
      const bool isOrd = (tt > 0.f) && (fabsf(tt - vk) <= DELTA);
      const bool cand = isOrd || (isEps && nearEps);
      const bool defIn = (tt > vk + DELTA) && !cand;
      if (defIn) {
        att[(size_t)n * N_CTX + mL[idx]] = tt;
        ++gLoc;
      }
      if (cand) {
        int p2 = atomicAdd(&lc, 1);
        if (p2 < CAP) { cM[p2] = mL[idx]; cV[p2] = tt; }
      }
    }
  }
#pragma unroll
  for (int off = 32; off; off >>= 1) gLoc += __shfl_down(gLoc, off, 64);
  const int g = __shfl(gLoc, 0, 64);
  __syncthreads();
  int c = lc;
  if (c > CAP) c = CAP;
  if (c == 0) return;
  const int slots = TOPK_K - g;

  if (c <= slots && !nearEps) {
    if (j < c) att[(size_t)n * N_CTX + cM[j]] = cV[j];
    return;
  }

  // refined triage (R23 phase-b verbatim, on cM)
  __shared__ float rv_s[CAP];
  __shared__ float rr_s[CAP];
  const float* cn = ctx + (size_t)n * DIM;
  for (int q = 0; q < c; ++q) {
    const int mq = cM[q];
    const float* cm = ctx + (size_t)mq * DIM;
    float acc8[8] = {0.f, 0.f, 0.f, 0.f, 0.f, 0.f, 0.f, 0.f};
    for (int p = 0; p < NPERS; ++p) {
      const float sA = invr[(size_t)p * N_CTX + n];
      const float sB = invr[(size_t)p * N_CTX + mq];
      const float* wp = w + (size_t)p * DIM;
#pragma unroll
      for (int i2 = 0; i2 < 8; ++i2) {
        const int d = j + 64 * i2;
        const float fa = (cn[d] * wp[d]) * sA;
        const float fb = (cm[d] * wp[d]) * sB;
        acc8[i2] = fmaf(fa, fb, acc8[i2]);
      }
    }
    float part = ((acc8[0] + acc8[1]) + (acc8[2] + acc8[3])) +
                 ((acc8[4] + acc8[5]) + (acc8[6] + acc8[7]));
#pragma unroll
    for (int off = 32; off; off >>= 1) part += __shfl_down(part, off, 64);
    if (j == 0) {
      rr_s[q] = part;
      rv_s[q] = (part > EPS_NN) ? part : 0.f;
    }
  }
  __syncthreads();

  bool kept = false;
  float rv = 0.f, rr = 0.f;
  if (j < c) {
    rv = rv_s[j];
    rr = rr_s[j];
    const int m = cM[j];
    int rank = 0;
    for (int i = 0; i < c; ++i) {
      if (i == j) continue;
      rank += ((rv_s[i] > rv) || (rv_s[i] == rv && cM[i] < m)) ? 1 : 0;
    }
    kept = (rank < slots);
  }
  float mk = (j < c && kept) ? rv : 3.4e38f;
  float mo = (j < c && !kept) ? rv : -3.4e38f;
  float ea = (j < c && fabsf(rr - EPS_NN) <= DELTA2) ? 1.f : 0.f;
#pragma unroll
  for (int off = 32; off; off >>= 1) {
    mk = fminf(mk, __shfl_down(mk, off, 64));
    mo = fmaxf(mo, __shfl_down(mo, off, 64));
    ea = fmaxf(ea, __shfl_down(ea, off, 64));
  }
  mk = __shfl(mk, 0, 64);
  mo = __shfl(mo, 0, 64);
  ea = __shfl(ea, 0, 64);
  const bool ambiguous = (mk - mo <= DELTA2) || (ea > 0.f);

  if (ambiguous) {
    if (j < c) candM[n * CAP + j] = cM[j];
    if (j == 0) {
      cnt_g[4 * n] = c;
      cnt_g[4 * n + 1] = g;
      int gp = atomicAdd(gcount, 1);
      glist[gp] = n;
    }
    return;
  }
  if (j < c && kept) att[(size_t)n * N_CTX + cM[j]] = rv;
}

// ---------------------------------------------------------------------------
// Kernel 5: exact chain for ambiguous rows (R23 verbatim; LDS operands;
// bit-identical to the locked R2 chain).
// ---------------------------------------------------------------------------
__global__ __launch_bounds__(64) void repair_chain(
    const float* __restrict__ ctx, const float* __restrict__ w,
    const float* __restrict__ invr, const int* __restrict__ candM,
    const int* __restrict__ cnt_g, const int* __restrict__ glist,
    const int* __restrict__ gcount, float* __restrict__ att) {
  if (blockIdx.x >= gcount[0]) return;
  const int n = glist[blockIdx.x];
  const int c = cnt_g[4 * n];
  const int slots = TOPK_K - cnt_g[4 * n + 1];
  const int j = threadIdx.x;

  __shared__ __align__(16) float wL[KTOT];
  __shared__ __align__(16) float cnL[DIM];
  __shared__ __align__(16) float cmL[CAPL][516];
  __shared__ float te_s[CAP];
  __shared__ int m_s[CAP];

  if (j < c) m_s[j] = candM[n * CAP + j];
  __syncthreads();

  {
    const float4* wg = reinterpret_cast<const float4*>(w);
    float4* wl = reinterpret_cast<float4*>(wL);
#pragma unroll
    for (int i = 0; i < 32; ++i) wl[i * 64 + j] = wg[i * 64 + j];
    const float4* cg = reinterpret_cast<const float4*>(ctx + (size_t)n * DIM);
    float4* cl = reinterpret_cast<float4*>(cnL);
#pragma unroll
    for (int i = 0; i < 2; ++i) cl[i * 64 + j] = cg[i * 64 + j];
    const int cl2 = (c < CAPL) ? c : CAPL;
    for (int r = 0; r < cl2; ++r) {
      const float4* mg = reinterpret_cast<const float4*>(ctx + (size_t)m_s[r] * DIM);
      float4* ml = reinterpret_cast<float4*>(&cmL[r][0]);
#pragma unroll
      for (int i = 0; i < 2; ++i) ml[i * 64 + j] = mg[i * 64 + j];
    }
  }
  __syncthreads();

  float te = -1.f;
  int m = -1;
  if (j < c) {
    m = m_s[j];
    const float4* cn4 = reinterpret_cast<const float4*>(cnL);
    const float4* cm4 = (j < CAPL)
        ? reinterpret_cast<const float4*>(&cmL[j][0])
        : reinterpret_cast<const float4*>(ctx + (size_t)m * DIM);
    float e = 0.f;
    for (int p = 0; p < NPERS; ++p) {
      const float sA = invr[(size_t)p * N_CTX + n];
      const float sB = invr[(size_t)p * N_CTX + m];
      const float4* w4 = reinterpret_cast<const float4*>(wL + p * DIM);
#pragma unroll 4
      for (int q = 0; q < DIM / 4; ++q) {
        const float4 a = cn4[q], b = cm4[q], ww = w4[q];
        e = fmaf((a.x * ww.x) * sA, (b.x * ww.x) * sB, e);
        e = fmaf((a.y * ww.y) * sA, (b.y * ww.y) * sB, e);
        e = fmaf((a.z * ww.z) * sA, (b.z * ww.z) * sB, e);
        e = fmaf((a.w * ww.w) * sA, (b.w * ww.w) * sB, e);
      }
    }
    te = (e > EPS_NN) ? e : 0.f;
  }
  te_s[j] = te;
  __syncthreads();
  if (j < c) {
    int rank = 0;
    for (int i = 0; i < c; ++i) {
      if (i == j) continue;
      rank += ((te_s[i] > te) || (te_s[i] == te && m_s[i] < m)) ? 1 : 0;
    }
    if (rank < slots) att[(size_t)n * N_CTX + m] = te;
  }
}

// ---------------------------------------------------------------------------
extern "C" void kernel_launch(void* const* d_in, const int* in_sizes, int n_in,
                              void* d_out, int out_size, void* d_ws, size_t ws_size,
                              hipStream_t stream) {
  const float* ctx = (const float*)d_in[0];   // (4096, 512)
  const float* w   = (const float*)d_in[1];   // (16, 512)
  float* out = (float*)d_out;                 // (4096, 4096)

  // ws: invr 256K | cnt_g 64K | candM 1M | candV 1M | glist 16K | gcount 4K |
  //     rcnt 16K | rlistM 4M | rlistV 4M | Fhi 64M
  const size_t OFF_CNT = 262144;
  const size_t OFF_CAND = OFF_CNT + 65536;
  const size_t OFF_CV = OFF_CAND + 1048576;
  const size_t OFF_GL = OFF_CV + 1048576;
  const size_t OFF_GC = OFF_GL + 16384;
  const size_t OFF_RC = OFF_GC + 4096;
  const size_t OFF_RM = OFF_RC + 16384;
  const size_t OFF_RV = OFF_RM + 4194304;
  const size_t OFF_FHI = OFF_RV + 4194304;
  const size_t FSZ = (size_t)32 * NKSTEP * CHUNK;       // 67108864
  float* invr = (float*)d_ws;
  int* cnt_g = (int*)((char*)d_ws + OFF_CNT);
  int* candM = (int*)((char*)d_ws + OFF_CAND);
  float* candV = (float*)((char*)d_ws + OFF_CV);
  int* glist = (int*)((char*)d_ws + OFF_GL);
  int* gcount = (int*)((char*)d_ws + OFF_GC);
  int* rcnt = (int*)((char*)d_ws + OFF_RC);
  int* rlistM = (int*)((char*)d_ws + OFF_RM);
  float* rlistV = (float*)((char*)d_ws + OFF_RV);
  unsigned short* Fhi = (unsigned short*)((char*)d_ws + OFF_FHI);
  const bool haveF = ws_size >= OFF_FHI + FSZ;

  // output starts poisoned; zero it (output = zeros + sparse selected values)
  hipMemsetAsync(out, 0, (size_t)N_CTX * N_CTX * sizeof(float), stream);

  if (haveF) {
    split_norms_kernel<<<(N_CTX * 64) / 256, 256, 0, stream>>>(ctx, w, invr, Fhi,
                                                               gcount, rcnt);
    att_gemm_fast<<<528, 256, 0, stream>>>(Fhi, rcnt, rlistM, rlistV);
    select_compact<<<N_CTX, 64, 0, stream>>>(ctx, w, invr, rcnt, rlistM, rlistV,
                                             candM, cnt_g, glist, gcount, out);
  } else {
    norms_kernel<<<(NPERS * N_CTX) / 4, 256, 0, stream>>>(ctx, w, invr, gcount);
    dim3 grid(N_CTX / BM, N_CTX / BM);
    att_gemm<<<grid, 256, 0, stream>>>(ctx, w, invr, out);
    topk_scan<<<N_CTX, 256, 0, stream>>>(out, candM, candV, cnt_g);
    repair_select<<<N_CTX, 64, 0, stream>>>(ctx, w, invr, candM, candV, cnt_g,
                                            glist, gcount, out);
  }

  repair_chain<<<N_CTX, 64, 0, stream>>>(ctx, w, invr, candM, cnt_g,
                                         glist, gcount, out);
}

// Round 25
// 369.918 us; speedup vs baseline: 1.8213x; 1.0811x over previous
//
#include <hip/hip_runtime.h>
#include <math.h>
#include <stdint.h>

#define N_CTX 4096
#define DIM 512
#define NPERS 16
#define KTOT (NPERS * DIM)   // 8192
#define EPS_NN 0.1f
#define TOPK_K 30

#define DELTA 4e-4f          // GEMM-vs-chain margin (validated R18+)
#define DELTA2 1e-5f         // refined-vs-chain margin (order noise ~4e-7 RMS)
#define CAP 64               // max candidates per row
#define CAPL 12              // cm rows staged in LDS inside repair_chain
#define RCAP 256             // compact list capacity per row (~47 expected)
#define LCAP 8               // per-(row,tile) LDS buffer entries

#define BM 128
#define BK 64
#define NKSTEP (KTOT / BK)   // 128
#define CHUNK 16384

typedef __attribute__((ext_vector_type(8))) short bfrag;
typedef __attribute__((ext_vector_type(4))) float f32x4;

__device__ __forceinline__ unsigned short f2bf(float f) {
  unsigned u = __float_as_uint(f);
  unsigned r = u + 0x7FFFu + ((u >> 16) & 1u);
  return (unsigned short)(r >> 16);
}

#define SWZ(r, b) ((b) ^ (((r) & 7) << 4))

__device__ __forceinline__ void stage1k(const char* gsrc, char* ldst, int lane) {
#if __has_builtin(__builtin_amdgcn_global_load_lds)
  __builtin_amdgcn_global_load_lds(
      (const __attribute__((address_space(1))) unsigned int*)(uintptr_t)(gsrc + lane * 16),
      (__attribute__((address_space(3))) unsigned int*)(uintptr_t)ldst, 16, 0, 0);
#else
  *reinterpret_cast<uint4*>(ldst + lane * 16) =
      *reinterpret_cast<const uint4*>(gsrc + lane * 16);
#endif
}

// ---------------------------------------------------------------------------
// Kernel 1 (fallback only)
// ---------------------------------------------------------------------------
__global__ __launch_bounds__(256) void norms_kernel(
    const float* __restrict__ ctx, const float* __restrict__ w,
    float* __restrict__ invr, int* __restrict__ gcount) {
  int wid = threadIdx.x >> 6;
  int lane = threadIdx.x & 63;
  int gid = blockIdx.x * 4 + wid;
  if (blockIdx.x == 0 && threadIdx.x == 0) gcount[0] = 0;
  int p = gid >> 12;
  int n = gid & (N_CTX - 1);
  const float4* c4 = reinterpret_cast<const float4*>(ctx + (size_t)n * DIM + lane * 8);
  const float4* w4 = reinterpret_cast<const float4*>(w + (size_t)p * DIM + lane * 8);
  float4 c0 = c4[0], c1 = c4[1];
  float4 w0 = w4[0], w1 = w4[1];
  float s = 0.f, v;
  v = c0.x * w0.x; s = fmaf(v, v, s);
  v = c0.y * w0.y; s = fmaf(v, v, s);
  v = c0.z * w0.z; s = fmaf(v, v, s);
  v = c0.w * w0.w; s = fmaf(v, v, s);
  v = c1.x * w1.x; s = fmaf(v, v, s);
  v = c1.y * w1.y; s = fmaf(v, v, s);
  v = c1.z * w1.z; s = fmaf(v, v, s);
  v = c1.w * w1.w; s = fmaf(v, v, s);
#pragma unroll
  for (int off = 32; off; off >>= 1) s += __shfl_down(s, off, 64);
  if (lane == 0) invr[(size_t)p * N_CTX + n] = 0.25f / fmaxf(sqrtf(s), 1e-12f);
}

// ---------------------------------------------------------------------------
// Kernel 1+1b FUSED: norms (bit-identical chain) + bf16-hi split.
// ---------------------------------------------------------------------------
__global__ __launch_bounds__(256) void split_norms_kernel(
    const float* __restrict__ ctx, const float* __restrict__ w,
    float* __restrict__ invr, unsigned short* __restrict__ Fhi,
    int* __restrict__ gcount, int* __restrict__ rcnt) {
  const int tid = blockIdx.x * 256 + threadIdx.x;
  if (tid == 0) gcount[0] = 0;
  if (tid < N_CTX) rcnt[tid] = 0;
  const int n = tid >> 6;
  const int db = tid & 63;
  const int d0 = db * 8;
  const int P = n >> 7;
  const int r = n & 127;
  const int sl = db & 7;
  const int swzoff = r * 128 + ((sl * 16) ^ ((r & 7) << 4));

  const float4 c0 = *reinterpret_cast<const float4*>(ctx + (size_t)n * DIM + d0);
  const float4 c1 = *reinterpret_cast<const float4*>(ctx + (size_t)n * DIM + d0 + 4);

#pragma unroll
  for (int p = 0; p < NPERS; ++p) {
    const float4 w0 = *reinterpret_cast<const float4*>(w + (size_t)p * DIM + d0);
    const float4 w1 = *reinterpret_cast<const float4*>(w + (size_t)p * DIM + d0 + 4);

    float pr[8] = {c0.x * w0.x, c0.y * w0.y, c0.z * w0.z, c0.w * w0.w,
                   c1.x * w1.x, c1.y * w1.y, c1.z * w1.z, c1.w * w1.w};

    float s = 0.f;
#pragma unroll
    for (int j = 0; j < 8; ++j) s = fmaf(pr[j], pr[j], s);
#pragma unroll
    for (int off = 32; off; off >>= 1) s += __shfl_down(s, off, 64);
    const float stot = __shfl(s, 0, 64);
    const float sc = 0.25f / fmaxf(sqrtf(stot), 1e-12f);
    if (db == 0) invr[(size_t)p * N_CTX + n] = sc;

    unsigned hb[8];
#pragma unroll
    for (int j = 0; j < 8; ++j) hb[j] = f2bf(pr[j] * sc);
    uint4 hv = make_uint4(hb[0] | (hb[1] << 16), hb[2] | (hb[3] << 16),
                          hb[4] | (hb[5] << 16), hb[6] | (hb[7] << 16));
    const int kstep = p * 8 + (db >> 3);
    const size_t base = (size_t)(P * 128 + kstep) * CHUNK + swzoff;
    *reinterpret_cast<uint4*>((char*)Fhi + base) = hv;
  }
}

// ---------------------------------------------------------------------------
// Kernel 2 (fast): single-product bf16 MFMA GEMM with compact output.
// R25: epilogue hits buffered in LDS (per-tile-row lists, LDS atomics),
// then flushed with ONE parallel global atomic per touched row — removes
// R24's serialized dependent global-atomic chains. Same entries, order
// permuted (output invariant: selection ranks by (value,index)).
// ---------------------------------------------------------------------------
__global__ __launch_bounds__(256, 3) void att_gemm_fast(
    const unsigned short* __restrict__ Fhi, int* __restrict__ rcnt,
    int* __restrict__ rlistM, float* __restrict__ rlistV) {
  const int bid0 = blockIdx.x;
  int bid = (bid0 & 7) * 66 + (bid0 >> 3);
  int by = 0;
  while (bid >= (by + 1) * 32 - ((by + 1) * by) / 2) ++by;
  const int bx = by + (bid - (by * 32 - (by * (by - 1)) / 2));

  __shared__ __align__(16) char Ahi[CHUNK];
  __shared__ __align__(16) char Bhi[CHUNK];
  __shared__ int lcnt2[256];          // straight rows 0..127, mirror 128..255
  __shared__ int2 lent[256][LCAP];    // (col, val bits)

  const int t = threadIdx.x;
  const int lane = t & 63, wid = t >> 6;
  const int wr = wid >> 1, wc = wid & 1;
  const int woff = __builtin_amdgcn_readfirstlane(wid * 4096);

  lcnt2[t] = 0;                       // t covers all 256 slots

  const char* gAh = (const char*)Fhi + (size_t)by * NKSTEP * CHUNK + woff;
  const char* gBh = (const char*)Fhi + (size_t)bx * NKSTEP * CHUNK + woff;

  f32x4 acc[4][4] = {};

  for (int s = 0; s < NKSTEP; ++s) {
    const size_t so = (size_t)s * CHUNK;
#pragma unroll
    for (int i = 0; i < 4; ++i) {
      stage1k(gAh + so + i * 1024, Ahi + woff + i * 1024, lane);
      stage1k(gBh + so + i * 1024, Bhi + woff + i * 1024, lane);
    }
    __syncthreads();

#pragma unroll
    for (int ks = 0; ks < 2; ++ks) {
      const int kb = ks * 64 + (lane >> 4) * 16;
      bfrag ah[4], bh[4];
#pragma unroll
      for (int m = 0; m < 4; ++m) {
        const int r = wr * 64 + m * 16 + (lane & 15);
        ah[m] = *reinterpret_cast<const bfrag*>(Ahi + r * 128 + SWZ(r, kb));
      }
#pragma unroll
      for (int n2 = 0; n2 < 4; ++n2) {
        const int r = wc * 64 + n2 * 16 + (lane & 15);
        bh[n2] = *reinterpret_cast<const bfrag*>(Bhi + r * 128 + SWZ(r, kb));
      }
#pragma unroll
      for (int m = 0; m < 4; ++m)
#pragma unroll
        for (int n2 = 0; n2 < 4; ++n2)
          acc[m][n2] = __builtin_amdgcn_mfma_f32_16x16x32_bf16(ah[m], bh[n2], acc[m][n2], 0, 0, 0);
    }
    __syncthreads();
  }

  const int Ro = by * BM, Co = bx * BM;
  const int col = lane & 15, rq = (lane >> 4) * 4;
  const float TH = EPS_NN - DELTA;
#pragma unroll
  for (int m = 0; m < 4; ++m)
#pragma unroll
    for (int n2 = 0; n2 < 4; ++n2) {
      const int lr = wr * 64 + m * 16 + rq;         // local row base
      const int lcol = wc * 64 + n2 * 16 + col;     // local col
#pragma unroll
      for (int j = 0; j < 4; ++j) {
        const float v = acc[m][n2][j];
        if (v > TH) {
          const int slot = lr + j;                  // 0..127
          int p = atomicAdd(&lcnt2[slot], 1);
          if (p < LCAP) {
            lent[slot][p] = make_int2(Co + lcol, __float_as_int(v));
          } else {                                  // rare overflow: direct
            int pos = atomicAdd(&rcnt[Ro + slot], 1);
            if (pos < RCAP) {
              rlistM[(size_t)(Ro + slot) * RCAP + pos] = Co + lcol;
              rlistV[(size_t)(Ro + slot) * RCAP + pos] = v;
            }
          }
          if (bx != by) {
            const int slot2 = 128 + lcol;
            int p2 = atomicAdd(&lcnt2[slot2], 1);
            if (p2 < LCAP) {
              lent[slot2][p2] = make_int2(Ro + lr + j, __float_as_int(v));
            } else {
              int pos2 = atomicAdd(&rcnt[Co + lcol], 1);
              if (pos2 < RCAP) {
                rlistM[(size_t)(Co + lcol) * RCAP + pos2] = Ro + lr + j;
                rlistV[(size_t)(Co + lcol) * RCAP + pos2] = v;
              }
            }
          }
        }
      }
    }
  __syncthreads();

  // flush: thread t owns slot t; one parallel global atomic per touched row
  {
    const int s2 = t;
    const bool mirrorSlot = (s2 >= 128);
    if (!(mirrorSlot && bx == by)) {
      int cl = lcnt2[s2];
      if (cl > LCAP) cl = LCAP;
      if (cl > 0) {
        const int row = mirrorSlot ? (Co + (s2 - 128)) : (Ro + s2);
        int base = atomicAdd(&rcnt[row], cl);
        for (int i = 0; i < cl; ++i) {
          const int pos = base + i;
          if (pos < RCAP) {
            rlistM[(size_t)row * RCAP + pos] = lent[s2][i].x;
            rlistV[(size_t)row * RCAP + pos] = __int_as_float(lent[s2][i].y);
          }
        }
      }
    }
  }
}

// ---------------------------------------------------------------------------
// Kernel 2 (fallback): on-the-fly split + 3-product MFMA, dense stores.
// ---------------------------------------------------------------------------
__device__ __forceinline__ void stage_half(char* __restrict__ hi_base,
                                           char* __restrict__ lo_base,
                                           const float4* cv, const float4* wv,
                                           float s, int r, int h) {
  unsigned hu[16], lu[16];
#pragma unroll
  for (int i = 0; i < 8; ++i) {
    float f[4] = {cv[i].x * wv[i].x * s, cv[i].y * wv[i].y * s,
                  cv[i].z * wv[i].z * s, cv[i].w * wv[i].w * s};
    unsigned hb[4], lb[4];
#pragma unroll
    for (int j = 0; j < 4; ++j) {
      hb[j] = f2bf(f[j]);
      float hf = __uint_as_float(hb[j] << 16);
      lb[j] = f2bf(f[j] - hf);
    }
    hu[2 * i] = hb[0] | (hb[1] << 16);
    hu[2 * i + 1] = hb[2] | (hb[3] << 16);
    lu[2 * i] = lb[0] | (lb[1] << 16);
    lu[2 * i + 1] = lb[2] | (lb[3] << 16);
  }
#pragma unroll
  for (int c = 0; c < 4; ++c) {
    int boff = r * 128 + SWZ(r, h * 64 + c * 16);
    *reinterpret_cast<uint4*>(hi_base + boff) =
        make_uint4(hu[4 * c], hu[4 * c + 1], hu[4 * c + 2], hu[4 * c + 3]);
    *reinterpret_cast<uint4*>(lo_base + boff) =
        make_uint4(lu[4 * c], lu[4 * c + 1], lu[4 * c + 2], lu[4 * c + 3]);
  }
}

__global__ __launch_bounds__(256, 2) void att_gemm(
    const float* __restrict__ ctx, const float* __restrict__ w,
    const float* __restrict__ invr, float* __restrict__ out) {
  const int bx = blockIdx.x, by = blockIdx.y;
  if (by > bx) return;

  __shared__ __align__(16) char Ahi[BM * 128];
  __shared__ __align__(16) char Alo[BM * 128];
  __shared__ __align__(16) char Bhi[BM * 128];
  __shared__ __align__(16) char Blo[BM * 128];

  const int t = threadIdx.x;
  const int lane = t & 63, wid = t >> 6;
  const int wr = wid >> 1, wc = wid & 1;
  const int Ro = by * BM, Co = bx * BM;
  const int srow = t >> 1;
  const int sh = t & 1;

  f32x4 acc[4][4] = {};

  for (int k0 = 0; k0 < KTOT; k0 += BK) {
    const int p = k0 >> 9;
    const int d0 = (k0 & (DIM - 1)) + sh * 32;

    float4 cva[8], cvb[8], wv[8];
    const float* wrow = w + (size_t)p * DIM + d0;
    const float* arow = ctx + (size_t)(Ro + srow) * DIM + d0;
    const float* brow = ctx + (size_t)(Co + srow) * DIM + d0;
#pragma unroll
    for (int i = 0; i < 8; ++i) {
      wv[i] = *reinterpret_cast<const float4*>(wrow + 4 * i);
      cva[i] = *reinterpret_cast<const float4*>(arow + 4 * i);
      cvb[i] = *reinterpret_cast<const float4*>(brow + 4 * i);
    }
    const float sA = invr[(size_t)p * N_CTX + Ro + srow];
    const float sB = invr[(size_t)p * N_CTX + Co + srow];

    __syncthreads();
    stage_half(Ahi, Alo, cva, wv, sA, srow, sh);
    stage_half(Bhi, Blo, cvb, wv, sB, srow, sh);
    __syncthreads();

#pragma unroll
    for (int ks = 0; ks < 2; ++ks) {
      const int kb = ks * 64 + (lane >> 4) * 16;
      bfrag ah[4], al[4], bh[4], bl[4];
#pragma unroll
      for (int m = 0; m < 4; ++m) {
        const int r = wr * 64 + m * 16 + (lane & 15);
        const int off = r * 128 + SWZ(r, kb);
        ah[m] = *reinterpret_cast<const bfrag*>(Ahi + off);
        al[m] = *reinterpret_cast<const bfrag*>(Alo + off);
      }
#pragma unroll
      for (int n = 0; n < 4; ++n) {
        const int r = wc * 64 + n * 16 + (lane & 15);
        const int off = r * 128 + SWZ(r, kb);
        bh[n] = *reinterpret_cast<const bfrag*>(Bhi + off);
        bl[n] = *reinterpret_cast<const bfrag*>(Blo + off);
      }
#pragma unroll
      for (int m = 0; m < 4; ++m)
#pragma unroll
        for (int n = 0; n < 4; ++n) {
          acc[m][n] = __builtin_amdgcn_mfma_f32_16x16x32_bf16(ah[m], bh[n], acc[m][n], 0, 0, 0);
          acc[m][n] = __builtin_amdgcn_mfma_f32_16x16x32_bf16(ah[m], bl[n], acc[m][n], 0, 0, 0);
          acc[m][n] = __builtin_amdgcn_mfma_f32_16x16x32_bf16(al[m], bh[n], acc[m][n], 0, 0, 0);
        }
    }
  }

  const int col = lane & 15, rq = (lane >> 4) * 4;
#pragma unroll
  for (int m = 0; m < 4; ++m)
#pragma unroll
    for (int n = 0; n < 4; ++n) {
      const int gr = Ro + wr * 64 + m * 16 + rq;
      const int gc = Co + wc * 64 + n * 16 + col;
#pragma unroll
      for (int j = 0; j < 4; ++j)
        out[(size_t)(gr + j) * N_CTX + gc] = acc[m][n][j];
      if (bx != by) {
        *reinterpret_cast<float4*>(out + (size_t)gc * N_CTX + gr) =
            make_float4(acc[m][n][0], acc[m][n][1], acc[m][n][2], acc[m][n][3]);
      }
    }
}

// ---------------------------------------------------------------------------
// Kernel 3 (fallback): dense scan (R23 verbatim).
// ---------------------------------------------------------------------------
__global__ __launch_bounds__(256) void topk_scan(
    float* __restrict__ att, int* __restrict__ candM,
    float* __restrict__ candV, int* __restrict__ cnt_g) {
  __shared__ unsigned red[2][4];
  __shared__ int lcnt, lg;

  const int n = blockIdx.x;
  const int t = threadIdx.x;
  const int wid = t >> 6, lane = t & 63;
  float* row = att + (size_t)n * N_CTX;

  float ar[16], tr[16];
  unsigned ur[16];
#pragma unroll
  for (int i = 0; i < 4; ++i) {
    float4 v4 = *reinterpret_cast<const float4*>(row + (size_t)(i * 256 + t) * 4);
    float tmp[4] = {v4.x, v4.y, v4.z, v4.w};
#pragma unroll
    for (int j = 0; j < 4; ++j) {
      float a = tmp[j];
      float tt = (a > EPS_NN) ? a : 0.0f;
      ar[i * 4 + j] = a;
      tr[i * 4 + j] = tt;
      ur[i * 4 + j] = __float_as_uint(tt);
    }
  }
  if (t == 0) { lcnt = 0; lg = 0; }

  unsigned lo = 0u, hi = 0x7F800000u;
  int buf = 0;
  while (lo < hi) {
    unsigned mid = lo + ((hi - lo) >> 1);
    unsigned c = 0;
#pragma unroll
    for (int i = 0; i < 16; ++i) c += (ur[i] > mid) ? 1u : 0u;
#pragma unroll
    for (int off = 32; off; off >>= 1) c += __shfl_down(c, off, 64);
    if (lane == 0) red[buf][wid] = c;
    __syncthreads();
    unsigned tot = red[buf][0] + red[buf][1] + red[buf][2] + red[buf][3];
    if (tot < TOPK_K) hi = mid; else lo = mid + 1;
    buf ^= 1;
  }
  const float vk = __uint_as_float(lo);
  const bool nearEps = (vk <= EPS_NN + 2.0f * DELTA);
  __syncthreads();

  unsigned myg = 0;
#pragma unroll
  for (int i = 0; i < 16; ++i) {
    const int blk = i >> 2, j = i & 3;
    const int m = (blk * 256 + t) * 4 + j;
    const float a = ar[i], tt = tr[i];
    const bool isEps = fabsf(a - EPS_NN) <= DELTA;
    const bool isOrd = (tt > 0.f) && (fabsf(tt - vk) <= DELTA);
    const bool cand = isOrd || (isEps && nearEps);
    const bool defIn = (tt > vk + DELTA) && !cand;
    tr[i] = defIn ? tt : 0.f;
    myg += defIn ? 1u : 0u;
    unsigned long long mask = __ballot(cand);
    if (mask) {
      int base = 0;
      if (lane == 0) base = atomicAdd(&lcnt, (int)__popcll(mask));
      base = __shfl(base, 0, 64);
      if (cand) {
        int pos = base + (int)__popcll(mask & ((1ull << lane) - 1ull));
        if (pos < CAP) {
          candM[n * CAP + pos] = m;
          candV[n * CAP + pos] = tt;
        }
      }
    }
  }
#pragma unroll
  for (int off = 32; off; off >>= 1) myg += __shfl_down(myg, off, 64);
  if (lane == 0) atomicAdd(&lg, (int)myg);

#pragma unroll
  for (int i = 0; i < 4; ++i) {
    *reinterpret_cast<float4*>(row + (size_t)(i * 256 + t) * 4) =
        make_float4(tr[i * 4], tr[i * 4 + 1], tr[i * 4 + 2], tr[i * 4 + 3]);
  }
  __syncthreads();
  if (t == 0) {
    cnt_g[4 * n] = (lcnt < CAP) ? lcnt : CAP;
    cnt_g[4 * n + 1] = lg;
    cnt_g[4 * n + 2] = nearEps ? 1 : 0;
  }
}

// ---------------------------------------------------------------------------
// Kernel 4 (fallback): R23 triage verbatim (skip + refined + defer).
// ---------------------------------------------------------------------------
__global__ __launch_bounds__(64) void repair_select(
    const float* __restrict__ ctx, const float* __restrict__ w,
    const float* __restrict__ invr, const int* __restrict__ candM,
    const float* __restrict__ candV, const int* __restrict__ cnt_g,
    int* __restrict__ glist, int* __restrict__ gcount,
    float* __restrict__ att) {
  const int n = blockIdx.x;
  const int c = cnt_g[4 * n];
  if (c == 0) return;
  const int slots = TOPK_K - cnt_g[4 * n + 1];
  const int nearEps = cnt_g[4 * n + 2];
  const int j = threadIdx.x;

  if (c <= slots && !nearEps) {
    if (j < c) att[(size_t)n * N_CTX + candM[n * CAP + j]] = candV[n * CAP + j];
    return;
  }

  __shared__ int m_s[CAP];
  __shared__ float rv_s[CAP];
  __shared__ float rr_s[CAP];
  if (j < c) m_s[j] = candM[n * CAP + j];
  __syncthreads();

  const float* cn = ctx + (size_t)n * DIM;
  for (int q = 0; q < c; ++q) {
    const int mq = m_s[q];
    const float* cm = ctx + (size_t)mq * DIM;
    float acc8[8] = {0.f, 0.f, 0.f, 0.f, 0.f, 0.f, 0.f, 0.f};
    for (int p = 0; p < NPERS; ++p) {
      const float sA = invr[(size_t)p * N_CTX + n];
      const float sB = invr[(size_t)p * N_CTX + mq];
      const float* wp = w + (size_t)p * DIM;
#pragma unroll
      for (int i2 = 0; i2 < 8; ++i2) {
        const int d = j + 64 * i2;
        const float fa = (cn[d] * wp[d]) * sA;
        const float fb = (cm[d] * wp[d]) * sB;
        acc8[i2] = fmaf(fa, fb, acc8[i2]);
      }
    }
    float part = ((acc8[0] + acc8[1]) + (acc8[2] + acc8[3])) +
                 ((acc8[4] + acc8[5]) + (acc8[6] + acc8[7]));
#pragma unroll
    for (int off = 32; off; off >>= 1) part += __shfl_down(part, off, 64);
    if (j == 0) {
      rr_s[q] = part;
      rv_s[q] = (part > EPS_NN) ? part : 0.f;
    }
  }
  __syncthreads();

  bool kept = false;
  float rv = 0.f, rr = 0.f;
  if (j < c) {
    rv = rv_s[j];
    rr = rr_s[j];
    const int m = m_s[j];
    int rank = 0;
    for (int i = 0; i < c; ++i) {
      if (i == j) continue;
      rank += ((rv_s[i] > rv) || (rv_s[i] == rv && m_s[i] < m)) ? 1 : 0;
    }
    kept = (rank < slots);
  }
  float mk = (j < c && kept) ? rv : 3.4e38f;
  float mo = (j < c && !kept) ? rv : -3.4e38f;
  float ea = (j < c && fabsf(rr - EPS_NN) <= DELTA2) ? 1.f : 0.f;
#pragma unroll
  for (int off = 32; off; off >>= 1) {
    mk = fminf(mk, __shfl_down(mk, off, 64));
    mo = fmaxf(mo, __shfl_down(mo, off, 64));
    ea = fmaxf(ea, __shfl_down(ea, off, 64));
  }
  mk = __shfl(mk, 0, 64);
  mo = __shfl(mo, 0, 64);
  ea = __shfl(ea, 0, 64);
  const bool ambiguous = (mk - mo <= DELTA2) || (ea > 0.f);

  if (ambiguous) {
    if (j == 0) {
      int gp = atomicAdd(gcount, 1);
      glist[gp] = n;
    }
    return;
  }
  if (j < c && kept) att[(size_t)n * N_CTX + m_s[j]] = rv;
}

// ---------------------------------------------------------------------------
// Kernel 4' (fast path): fused select on COMPACT lists (R24 verbatim).
// ---------------------------------------------------------------------------
__global__ __launch_bounds__(64) void select_compact(
    const float* __restrict__ ctx, const float* __restrict__ w,
    const float* __restrict__ invr, const int* __restrict__ rcnt,
    const int* __restrict__ rlistM, const float* __restrict__ rlistV,
    int* __restrict__ candM, int* __restrict__ cnt_g,
    int* __restrict__ glist, int* __restrict__ gcount,
    float* __restrict__ att) {
  const int n = blockIdx.x;
  const int j = threadIdx.x;
  int nc = rcnt[n];
  if (nc > RCAP) nc = RCAP;
  if (nc == 0) return;

  __shared__ int mL[RCAP];
  __shared__ float vL[RCAP];
  __shared__ float ttL[RCAP];
  __shared__ int cM[CAP];
  __shared__ float cV[CAP];
  __shared__ int lc;
  if (j == 0) lc = 0;
  for (int i = j; i < nc; i += 64) {
    const float a = rlistV[(size_t)n * RCAP + i];
    mL[i] = rlistM[(size_t)n * RCAP + i];
    vL[i] = a;
    ttL[i] = (a > EPS_NN) ? a : 0.f;
  }
  __syncthreads();

  float vkLoc = 3.4e38f;
  int posLoc = 0;
  float ttOwn[4];
#pragma unroll
  for (int s = 0; s < 4; ++s) ttOwn[s] = -1.f;
#pragma unroll
  for (int s = 0; s < 4; ++s) {
    const int idx = j + s * 64;
    if (idx < nc) {
      const float t = ttL[idx];
      ttOwn[s] = t;
      posLoc += (t > 0.f) ? 1 : 0;
      int g = 0;
      for (int i = 0; i < nc; ++i) g += (ttL[i] > t) ? 1 : 0;
      if (t > 0.f && g <= TOPK_K - 1) vkLoc = fminf(vkLoc, t);
    }
  }
#pragma unroll
  for (int off = 32; off; off >>= 1) {
    posLoc += __shfl_down(posLoc, off, 64);
    vkLoc = fminf(vkLoc, __shfl_down(vkLoc, off, 64));
  }
  const int pos = __shfl(posLoc, 0, 64);
  float vk = __shfl(vkLoc, 0, 64);
  if (pos < TOPK_K) vk = 0.f;
  const bool nearEps = (vk <= EPS_NN + 2.0f * DELTA);

  int gLoc = 0;
#pragma unroll
  for (int s = 0; s < 4; ++s) {
    const int idx = j + s * 64;
    if (idx < nc) {
      const float a = vL[idx], tt = ttOwn[s];
      const bool isEps = fabsf(a - EPS_NN) <= DELTA;
      const bool isOrd = (tt > 0.f) && (fabsf(tt - vk) <= DELTA);
      const bool cand = isOrd || (isEps && nearEps);
      const bool defIn = (tt > vk + DELTA) && !cand;
      if (defIn) {
        att[(size_t)n * N_CTX + mL[idx]] = tt;
        ++gLoc;
      }
      if (cand) {
        int p2 = atomicAdd(&lc, 1);
        if (p2 < CAP) { cM[p2] = mL[idx]; cV[p2] = tt; }
      }
    }
  }
#pragma unroll
  for (int off = 32; off; off >>= 1) gLoc += __shfl_down(gLoc, off, 64);
  const int g = __shfl(gLoc, 0, 64);
  __syncthreads();
  int c = lc;
  if (c > CAP) c = CAP;
  if (c == 0) return;
  const int slots = TOPK_K - g;

  if (c <= slots && !nearEps) {
    if (j < c) att[(size_t)n * N_CTX + cM[j]] = cV[j];
    return;
  }

  __shared__ float rv_s[CAP];
  __shared__ float rr_s[CAP];
  const float* cn = ctx + (size_t)n * DIM;
  for (int q = 0; q < c; ++q) {
    const int mq = cM[q];
    const float* cm = ctx + (size_t)mq * DIM;
    float acc8[8] = {0.f, 0.f, 0.f, 0.f, 0.f, 0.f, 0.f, 0.f};
    for (int p = 0; p < NPERS; ++p) {
      const float sA = invr[(size_t)p * N_CTX + n];
      const float sB = invr[(size_t)p * N_CTX + mq];
      const float* wp = w + (size_t)p * DIM;
#pragma unroll
      for (int i2 = 0; i2 < 8; ++i2) {
        const int d = j + 64 * i2;
        const float fa = (cn[d] * wp[d]) * sA;
        const float fb = (cm[d] * wp[d]) * sB;
        acc8[i2] = fmaf(fa, fb, acc8[i2]);
      }
    }
    float part = ((acc8[0] + acc8[1]) + (acc8[2] + acc8[3])) +
                 ((acc8[4] + acc8[5]) + (acc8[6] + acc8[7]));
#pragma unroll
    for (int off = 32; off; off >>= 1) part += __shfl_down(part, off, 64);
    if (j == 0) {
      rr_s[q] = part;
      rv_s[q] = (part > EPS_NN) ? part : 0.f;
    }
  }
  __syncthreads();

  bool kept = false;
  float rv = 0.f, rr = 0.f;
  if (j < c) {
    rv = rv_s[j];
    rr = rr_s[j];
    const int m = cM[j];
    int rank = 0;
    for (int i = 0; i < c; ++i) {
      if (i == j) continue;
      rank += ((rv_s[i] > rv) || (rv_s[i] == rv && cM[i] < m)) ? 1 : 0;
    }
    kept = (rank < slots);
  }
  float mk = (j < c && kept) ? rv : 3.4e38f;
  float mo = (j < c && !kept) ? rv : -3.4e38f;
  float ea = (j < c && fabsf(rr - EPS_NN) <= DELTA2) ? 1.f : 0.f;
#pragma unroll
  for (int off = 32; off; off >>= 1) {
    mk = fminf(mk, __shfl_down(mk, off, 64));
    mo = fmaxf(mo, __shfl_down(mo, off, 64));
    ea = fmaxf(ea, __shfl_down(ea, off, 64));
  }
  mk = __shfl(mk, 0, 64);
  mo = __shfl(mo, 0, 64);
  ea = __shfl(ea, 0, 64);
  const bool ambiguous = (mk - mo <= DELTA2) || (ea > 0.f);

  if (ambiguous) {
    if (j < c) candM[n * CAP + j] = cM[j];
    if (j == 0) {
      cnt_g[4 * n] = c;
      cnt_g[4 * n + 1] = g;
      int gp = atomicAdd(gcount, 1);
      glist[gp] = n;
    }
    return;
  }
  if (j < c && kept) att[(size_t)n * N_CTX + cM[j]] = rv;
}

// ---------------------------------------------------------------------------
// Kernel 5: exact chain for ambiguous rows (R23 verbatim; LDS operands;
// bit-identical to the locked R2 chain).
// ---------------------------------------------------------------------------
__global__ __launch_bounds__(64) void repair_chain(
    const float* __restrict__ ctx, const float* __restrict__ w,
    const float* __restrict__ invr, const int* __restrict__ candM,
    const int* __restrict__ cnt_g, const int* __restrict__ glist,
    const int* __restrict__ gcount, float* __restrict__ att) {
  if (blockIdx.x >= gcount[0]) return;
  const int n = glist[blockIdx.x];
  const int c = cnt_g[4 * n];
  const int slots = TOPK_K - cnt_g[4 * n + 1];
  const int j = threadIdx.x;

  __shared__ __align__(16) float wL[KTOT];
  __shared__ __align__(16) float cnL[DIM];
  __shared__ __align__(16) float cmL[CAPL][516];
  __shared__ float te_s[CAP];
  __shared__ int m_s[CAP];

  if (j < c) m_s[j] = candM[n * CAP + j];
  __syncthreads();

  {
    const float4* wg = reinterpret_cast<const float4*>(w);
    float4* wl = reinterpret_cast<float4*>(wL);
#pragma unroll
    for (int i = 0; i < 32; ++i) wl[i * 64 + j] = wg[i * 64 + j];
    const float4* cg = reinterpret_cast<const float4*>(ctx + (size_t)n * DIM);
    float4* cl = reinterpret_cast<float4*>(cnL);
#pragma unroll
    for (int i = 0; i < 2; ++i) cl[i * 64 + j] = cg[i * 64 + j];
    const int cl2 = (c < CAPL) ? c : CAPL;
    for (int r = 0; r < cl2; ++r) {
      const float4* mg = reinterpret_cast<const float4*>(ctx + (size_t)m_s[r] * DIM);
      float4* ml = reinterpret_cast<float4*>(&cmL[r][0]);
#pragma unroll
      for (int i = 0; i < 2; ++i) ml[i * 64 + j] = mg[i * 64 + j];
    }
  }
  __syncthreads();

  float te = -1.f;
  int m = -1;
  if (j < c) {
    m = m_s[j];
    const float4* cn4 = reinterpret_cast<const float4*>(cnL);
    const float4* cm4 = (j < CAPL)
        ? reinterpret_cast<const float4*>(&cmL[j][0])
        : reinterpret_cast<const float4*>(ctx + (size_t)m * DIM);
    float e = 0.f;
    for (int p = 0; p < NPERS; ++p) {
      const float sA = invr[(size_t)p * N_CTX + n];
      const float sB = invr[(size_t)p * N_CTX + m];
      const float4* w4 = reinterpret_cast<const float4*>(wL + p * DIM);
#pragma unroll 4
      for (int q = 0; q < DIM / 4; ++q) {
        const float4 a = cn4[q], b = cm4[q], ww = w4[q];
        e = fmaf((a.x * ww.x) * sA, (b.x * ww.x) * sB, e);
        e = fmaf((a.y * ww.y) * sA, (b.y * ww.y) * sB, e);
        e = fmaf((a.z * ww.z) * sA, (b.z * ww.z) * sB, e);
        e = fmaf((a.w * ww.w) * sA, (b.w * ww.w) * sB, e);
      }
    }
    te = (e > EPS_NN) ? e : 0.f;
  }
  te_s[j] = te;
  __syncthreads();
  if (j < c) {
    int rank = 0;
    for (int i = 0; i < c; ++i) {
      if (i == j) continue;
      rank += ((te_s[i] > te) || (te_s[i] == te && m_s[i] < m)) ? 1 : 0;
    }
    if (rank < slots) att[(size_t)n * N_CTX + m] = te;
  }
}

// ---------------------------------------------------------------------------
extern "C" void kernel_launch(void* const* d_in, const int* in_sizes, int n_in,
                              void* d_out, int out_size, void* d_ws, size_t ws_size,
                              hipStream_t stream) {
  const float* ctx = (const float*)d_in[0];   // (4096, 512)
  const float* w   = (const float*)d_in[1];   // (16, 512)
  float* out = (float*)d_out;                 // (4096, 4096)

  const size_t OFF_CNT = 262144;
  const size_t OFF_CAND = OFF_CNT + 65536;
  const size_t OFF_CV = OFF_CAND + 1048576;
  const size_t OFF_GL = OFF_CV + 1048576;
  const size_t OFF_GC = OFF_GL + 16384;
  const size_t OFF_RC = OFF_GC + 4096;
  const size_t OFF_RM = OFF_RC + 16384;
  const size_t OFF_RV = OFF_RM + 4194304;
  const size_t OFF_FHI = OFF_RV + 4194304;
  const size_t FSZ = (size_t)32 * NKSTEP * CHUNK;       // 67108864
  float* invr = (float*)d_ws;
  int* cnt_g = (int*)((char*)d_ws + OFF_CNT);
  int* candM = (int*)((char*)d_ws + OFF_CAND);
  float* candV = (float*)((char*)d_ws + OFF_CV);
  int* glist = (int*)((char*)d_ws + OFF_GL);
  int* gcount = (int*)((char*)d_ws + OFF_GC);
  int* rcnt = (int*)((char*)d_ws + OFF_RC);
  int* rlistM = (int*)((char*)d_ws + OFF_RM);
  float* rlistV = (float*)((char*)d_ws + OFF_RV);
  unsigned short* Fhi = (unsigned short*)((char*)d_ws + OFF_FHI);
  const bool haveF = ws_size >= OFF_FHI + FSZ;

  hipMemsetAsync(out, 0, (size_t)N_CTX * N_CTX * sizeof(float), stream);

  if (haveF) {
    split_norms_kernel<<<(N_CTX * 64) / 256, 256, 0, stream>>>(ctx, w, invr, Fhi,
                                                               gcount, rcnt);
    att_gemm_fast<<<528, 256, 0, stream>>>(Fhi, rcnt, rlistM, rlistV);
    select_compact<<<N_CTX, 64, 0, stream>>>(ctx, w, invr, rcnt, rlistM, rlistV,
                                             candM, cnt_g, glist, gcount, out);
  } else {
    norms_kernel<<<(NPERS * N_CTX) / 4, 256, 0, stream>>>(ctx, w, invr, gcount);
    dim3 grid(N_CTX / BM, N_CTX / BM);
    att_gemm<<<grid, 256, 0, stream>>>(ctx, w, invr, out);
    topk_scan<<<N_CTX, 256, 0, stream>>>(out, candM, candV, cnt_g);
    repair_select<<<N_CTX, 64, 0, stream>>>(ctx, w, invr, candM, candV, cnt_g,
                                            glist, gcount, out);
  }

  repair_chain<<<N_CTX, 64, 0, stream>>>(ctx, w, invr, candM, cnt_g,
                                         glist, gcount, out);
}